// Round 1
// baseline (946.296 us; speedup 1.0000x reference)
//
#include <hip/hip_runtime.h>
#include <math.h>

// SwinV2-3D block: RES=32, WS=8, SHIFT=4, NH=4, DIM=128, windows=64, N=512/window.
// Round 0: correctness-first fp32 baseline (no MFMA yet).

__device__ __forceinline__ int regionOf(int wb, int a) {
    // shifted-coord region along one axis: s = wb*8+a; 0 if s<24, 1 if 24<=s<28, 2 if s>=28
    return (wb < 3) ? 0 : ((a < 4) ? 1 : 2);
}

// ---------------- K0: CPB bias table: BT[3375][4] = 16*sigmoid(MLP(ctab)) ----------------
__global__ void k_bias_table(const float* __restrict__ w1, const float* __restrict__ b1,
                             const float* __restrict__ w2, float* __restrict__ BT) {
    int e = blockIdx.x;                       // 0..3374
    int id = e / 225, rem = e % 225, ih = rem / 15, iw = rem % 15;
    float ct[3];
    int ids[3] = {id, ih, iw};
#pragma unroll
    for (int a = 0; a < 3; ++a) {
        float r = (float)(ids[a] - 7) * (8.0f / 7.0f);
        float s = (r > 0.f) ? 1.f : ((r < 0.f) ? -1.f : 0.f);
        ct[a] = s * log2f(fabsf(r) + 1.0f) * (1.0f / 3.0f);   // /log2(8)
    }
    int t = threadIdx.x;                      // 128 threads
    float acc[4] = {0.f, 0.f, 0.f, 0.f};
    for (int j = t; j < 512; j += 128) {
        float hv = ct[0] * w1[j * 3 + 0] + ct[1] * w1[j * 3 + 1] + ct[2] * w1[j * 3 + 2] + b1[j];
        hv = fmaxf(hv, 0.f);
#pragma unroll
        for (int h = 0; h < 4; ++h) acc[h] += hv * w2[h * 512 + j];
    }
    __shared__ float red[4][128];
#pragma unroll
    for (int h = 0; h < 4; ++h) red[h][t] = acc[h];
    __syncthreads();
    if (t < 4) {
        float s = 0.f;
        for (int i = 0; i < 128; ++i) s += red[t][i];
        BT[e * 4 + t] = 16.0f / (1.0f + expf(-s));
    }
}

// ---------------- K1: roll+window gather + QKV GEMM + cosine norm (+scale into q) --------
// grid (8 token-tiles, 64 windows, 3 slabs {q,k,v}), block 256
__global__ void __launch_bounds__(256) k_qkv(
    const float* __restrict__ x, const float* __restrict__ qw, const float* __restrict__ qb,
    const float* __restrict__ ls, float* __restrict__ Qp, float* __restrict__ Kp,
    float* __restrict__ Vp) {
    const int tile = blockIdx.x;
    const int w = blockIdx.y;
    const int slab = blockIdx.z;
    const int tid = threadIdx.x;
    const int tx = tid & 31, ty = tid >> 5;
    const int wd = w >> 4, wh = (w >> 2) & 3, ww = w & 3;

    __shared__ __align__(16) float As[64][128];
    __shared__ __align__(16) float Wl[32][128];

    // stage A tile (64 tokens x 128 ch) with shift+window gather
#pragma unroll
    for (int q = 0; q < 8; ++q) {
        int lin = tid + 256 * q;
        int r = lin >> 5, f4i = lin & 31;
        int n = tile * 64 + r;
        int a = n >> 6, b = (n >> 3) & 7, c = n & 7;
        int od = (wd * 8 + a + 4) & 31, oh = (wh * 8 + b + 4) & 31, ow = (ww * 8 + c + 4) & 31;
        const float4* src = (const float4*)(x + ((od * 32 + oh) * 32 + ow) * 128);
        *(float4*)&As[r][f4i * 4] = src[f4i];
    }

    float acc[8][4];
#pragma unroll
    for (int i = 0; i < 8; ++i)
#pragma unroll
        for (int j = 0; j < 4; ++j) acc[i][j] = 0.f;

    const int slabbase = slab * 128;
    for (int kc = 0; kc < 4; ++kc) {
        __syncthreads();
#pragma unroll
        for (int q = 0; q < 4; ++q) {
            int lin = tid + 256 * q;          // 0..1023
            int col = lin >> 3, f4i = lin & 7;
            float4 wv = *(const float4*)(qw + (slabbase + col) * 128 + kc * 32 + f4i * 4);
            Wl[f4i * 4 + 0][col] = wv.x;
            Wl[f4i * 4 + 1][col] = wv.y;
            Wl[f4i * 4 + 2][col] = wv.z;
            Wl[f4i * 4 + 3][col] = wv.w;
        }
        __syncthreads();
#pragma unroll
        for (int k4 = 0; k4 < 8; ++k4) {
            float4 av[8];
#pragma unroll
            for (int ri = 0; ri < 8; ++ri)
                av[ri] = *(const float4*)&As[ty + 8 * ri][kc * 32 + k4 * 4];
#pragma unroll
            for (int j = 0; j < 4; ++j) {
                float wv[4];
#pragma unroll
                for (int ci = 0; ci < 4; ++ci) wv[ci] = Wl[k4 * 4 + j][tx + 32 * ci];
#pragma unroll
                for (int ri = 0; ri < 8; ++ri) {
                    float aval = (j == 0) ? av[ri].x : (j == 1) ? av[ri].y : (j == 2) ? av[ri].z : av[ri].w;
#pragma unroll
                    for (int ci = 0; ci < 4; ++ci) acc[ri][ci] += aval * wv[ci];
                }
            }
        }
    }

    float* dst = (slab == 0) ? Qp : (slab == 1) ? Kp : Vp;
    float scale[4];
    if (slab == 0) {
#pragma unroll
        for (int ci = 0; ci < 4; ++ci) scale[ci] = expf(fminf(ls[ci], 4.6051701859880914f));
    }
#pragma unroll
    for (int ri = 0; ri < 8; ++ri) {
        int r = ty + 8 * ri;
        int n = tile * 64 + r;
#pragma unroll
        for (int ci = 0; ci < 4; ++ci) {
            float v = acc[ri][ci] + qb[slabbase + tx + 32 * ci];
            if (slab < 2) {  // cosine normalization for q,k (head=ci, d=tx)
                float ss = v * v;
#pragma unroll
                for (int m = 1; m < 32; m <<= 1) ss += __shfl_xor(ss, m);
                v = v / (sqrtf(ss) + 1e-12f);
                if (slab == 0) v *= scale[ci];
            }
            dst[((w * 4 + ci) * 512 + n) * 32 + tx] = v;
        }
    }
}

// ---------------- K2: attention per (q-tile 16, head, window) ----------------
// S[16][512] in LDS; K staged [m][40]; V staged transposed [d][132]; split-m PV
__global__ void __launch_bounds__(256) k_attn(
    const float* __restrict__ Qp, const float* __restrict__ Kp, const float* __restrict__ Vp,
    const float* __restrict__ BT, float* __restrict__ AO) {
    const int qt = blockIdx.x;   // 0..31
    const int h = blockIdx.y;    // 0..3
    const int w = blockIdx.z;    // 0..63
    const int tid = threadIdx.x;
    const int wd = w >> 4, wh = (w >> 2) & 3, ww = w & 3;

    __shared__ __align__(16) float S[16][512];
    __shared__ __align__(16) float KV[5120];   // KT[m][40] (QK) / VT[d][132] (PV)
    __shared__ __align__(16) float Qs[16][32]; // also reused as PV cross-half reduce buf
    __shared__ float rinv[16];

    const int base = (w * 4 + h) * 512 * 32;

    if (tid < 128) {
        int r = tid >> 3, f4i = tid & 7;
        *(float4*)&Qs[r][f4i * 4] = *(const float4*)(Qp + base + (qt * 16 + r) * 32 + f4i * 4);
    }

    const int tx = tid & 31, ty = tid >> 5;
    // ---- QK^T + bias + mask -> S ----
    for (int mt = 0; mt < 4; ++mt) {
        __syncthreads();
#pragma unroll
        for (int q = 0; q < 4; ++q) {
            int lin = tid + 256 * q;
            int m = lin >> 3, f4i = lin & 7;
            *(float4*)&KV[m * 40 + f4i * 4] =
                *(const float4*)(Kp + base + (mt * 128 + m) * 32 + f4i * 4);
        }
        __syncthreads();
        float accq[2][4] = {};
#pragma unroll
        for (int d4 = 0; d4 < 8; ++d4) {
            float4 qv[2];
            qv[0] = *(const float4*)&Qs[ty][d4 * 4];
            qv[1] = *(const float4*)&Qs[ty + 8][d4 * 4];
#pragma unroll
            for (int ci = 0; ci < 4; ++ci) {
                float4 kv = *(const float4*)&KV[(tx + 32 * ci) * 40 + d4 * 4];
#pragma unroll
                for (int ri = 0; ri < 2; ++ri)
                    accq[ri][ci] += qv[ri].x * kv.x + qv[ri].y * kv.y + qv[ri].z * kv.z + qv[ri].w * kv.w;
            }
        }
#pragma unroll
        for (int ri = 0; ri < 2; ++ri) {
            int row = ty + 8 * ri;
            int n = qt * 16 + row;
            int an = n >> 6, bn = (n >> 3) & 7, cn = n & 7;
            int cntn = regionOf(wd, an) * 9 + regionOf(wh, bn) * 3 + regionOf(ww, cn);
#pragma unroll
            for (int ci = 0; ci < 4; ++ci) {
                int m = mt * 128 + tx + 32 * ci;
                int am = m >> 6, bm = (m >> 3) & 7, cm = m & 7;
                int cntm = regionOf(wd, am) * 9 + regionOf(wh, bm) * 3 + regionOf(ww, cm);
                int ridx = ((an - am + 7) * 15 + (bn - bm + 7)) * 15 + (cn - cm + 7);
                float bv = BT[ridx * 4 + h];
                float mk = (cntn == cntm) ? 0.f : -100.f;
                S[row][m] = accq[ri][ci] + bv + mk;
            }
        }
    }
    __syncthreads();
    // ---- softmax (full row in LDS); keep 1/sum, fold at PV epilogue ----
    {
        int wv = tid >> 6, lane = tid & 63;
        for (int rr = 0; rr < 4; ++rr) {
            int row = wv * 4 + rr;
            float v[8];
            float mx = -1e30f;
#pragma unroll
            for (int j = 0; j < 8; ++j) {
                v[j] = S[row][lane + 64 * j];
                mx = fmaxf(mx, v[j]);
            }
#pragma unroll
            for (int m = 1; m < 64; m <<= 1) mx = fmaxf(mx, __shfl_xor(mx, m));
            float sm = 0.f;
#pragma unroll
            for (int j = 0; j < 8; ++j) {
                v[j] = expf(v[j] - mx);
                sm += v[j];
            }
#pragma unroll
            for (int m = 1; m < 64; m <<= 1) sm += __shfl_xor(sm, m);
#pragma unroll
            for (int j = 0; j < 8; ++j) S[row][lane + 64 * j] = v[j];
            if (lane == 0) rinv[row] = 1.0f / sm;
        }
    }
    // ---- PV: thread = (4 rows, d=tx), m split in halves across ty>>2 ----
    const int rgrp = ty & 3, mhalf = ty >> 2;
    float accp[4] = {0.f, 0.f, 0.f, 0.f};
    for (int mt = 0; mt < 4; ++mt) {
        __syncthreads();
#pragma unroll
        for (int q = 0; q < 4; ++q) {
            int lin = tid + 256 * q;
            int m = lin >> 3, f4i = lin & 7;
            float4 vv = *(const float4*)(Vp + base + (mt * 128 + m) * 32 + f4i * 4);
            KV[(f4i * 4 + 0) * 132 + m] = vv.x;
            KV[(f4i * 4 + 1) * 132 + m] = vv.y;
            KV[(f4i * 4 + 2) * 132 + m] = vv.z;
            KV[(f4i * 4 + 3) * 132 + m] = vv.w;
        }
        __syncthreads();
#pragma unroll
        for (int m4 = 0; m4 < 16; ++m4) {
            int mi = mhalf * 16 + m4;
            float4 vv = *(const float4*)&KV[tx * 132 + mi * 4];
#pragma unroll
            for (int rr = 0; rr < 4; ++rr) {
                int row = rgrp * 4 + rr;
                float4 p = *(const float4*)&S[row][mt * 128 + mi * 4];
                accp[rr] += p.x * vv.x + p.y * vv.y + p.z * vv.z + p.w * vv.w;
            }
        }
    }
    __syncthreads();
    float* red = &Qs[0][0];   // 512 floats, free after QK phase
    if (mhalf == 1) {
#pragma unroll
        for (int rr = 0; rr < 4; ++rr) red[(rgrp * 4 + rr) * 32 + tx] = accp[rr];
    }
    __syncthreads();
    if (mhalf == 0) {
#pragma unroll
        for (int rr = 0; rr < 4; ++rr) {
            int row = rgrp * 4 + rr;
            float o = (accp[rr] + red[row * 32 + tx]) * rinv[row];
            AO[(w * 512 + qt * 16 + row) * 128 + h * 32 + tx] = o;
        }
    }
}

// ---------------- K3: proj + LN(norm1) + residual, scatter to spatial ----------------
__global__ void __launch_bounds__(256) k_proj_ln(
    const float* __restrict__ AO, const float* __restrict__ pw, const float* __restrict__ pb,
    const float* __restrict__ n1w, const float* __restrict__ n1b, const float* __restrict__ x,
    float* __restrict__ out) {
    const int tile = blockIdx.x;  // 0..7
    const int w = blockIdx.y;     // 0..63
    const int tid = threadIdx.x;
    const int tx = tid & 31, ty = tid >> 5;
    const int wd = w >> 4, wh = (w >> 2) & 3, ww = w & 3;

    __shared__ __align__(16) float As[64][128];
    __shared__ __align__(16) float Wl[32][128];

#pragma unroll
    for (int q = 0; q < 8; ++q) {
        int lin = tid + 256 * q;
        int r = lin >> 5, f4i = lin & 31;
        *(float4*)&As[r][f4i * 4] =
            *(const float4*)(AO + (w * 512 + tile * 64 + r) * 128 + f4i * 4);
    }

    float acc[8][4];
#pragma unroll
    for (int i = 0; i < 8; ++i)
#pragma unroll
        for (int j = 0; j < 4; ++j) acc[i][j] = 0.f;

    for (int kc = 0; kc < 4; ++kc) {
        __syncthreads();
#pragma unroll
        for (int q = 0; q < 4; ++q) {
            int lin = tid + 256 * q;
            int col = lin >> 3, f4i = lin & 7;
            float4 wv = *(const float4*)(pw + col * 128 + kc * 32 + f4i * 4);
            Wl[f4i * 4 + 0][col] = wv.x;
            Wl[f4i * 4 + 1][col] = wv.y;
            Wl[f4i * 4 + 2][col] = wv.z;
            Wl[f4i * 4 + 3][col] = wv.w;
        }
        __syncthreads();
#pragma unroll
        for (int k4 = 0; k4 < 8; ++k4) {
            float4 av[8];
#pragma unroll
            for (int ri = 0; ri < 8; ++ri)
                av[ri] = *(const float4*)&As[ty + 8 * ri][kc * 32 + k4 * 4];
#pragma unroll
            for (int j = 0; j < 4; ++j) {
                float wv[4];
#pragma unroll
                for (int ci = 0; ci < 4; ++ci) wv[ci] = Wl[k4 * 4 + j][tx + 32 * ci];
#pragma unroll
                for (int ri = 0; ri < 8; ++ri) {
                    float aval = (j == 0) ? av[ri].x : (j == 1) ? av[ri].y : (j == 2) ? av[ri].z : av[ri].w;
#pragma unroll
                    for (int ci = 0; ci < 4; ++ci) acc[ri][ci] += aval * wv[ci];
                }
            }
        }
    }

#pragma unroll
    for (int ri = 0; ri < 8; ++ri) {
        int r = ty + 8 * ri;
        int n = tile * 64 + r;
        float y[4];
        float s = 0.f, ssq = 0.f;
#pragma unroll
        for (int ci = 0; ci < 4; ++ci) {
            y[ci] = acc[ri][ci] + pb[tx + 32 * ci];
            s += y[ci];
            ssq += y[ci] * y[ci];
        }
#pragma unroll
        for (int m = 1; m < 32; m <<= 1) {
            s += __shfl_xor(s, m);
            ssq += __shfl_xor(ssq, m);
        }
        float mean = s * (1.0f / 128.0f);
        float var = ssq * (1.0f / 128.0f) - mean * mean;
        float rstd = rsqrtf(var + 1e-5f);
        int a = n >> 6, b = (n >> 3) & 7, c = n & 7;
        int od = (wd * 8 + a + 4) & 31, oh = (wh * 8 + b + 4) & 31, ow = (ww * 8 + c + 4) & 31;
        int off = ((od * 32 + oh) * 32 + ow) * 128;
#pragma unroll
        for (int ci = 0; ci < 4; ++ci) {
            int col = tx + 32 * ci;
            float ln = (y[ci] - mean) * rstd * n1w[col] + n1b[col];
            out[off + col] = x[off + col] + ln;
        }
    }
}

// ---------------- K4: MLP (fc1+gelu+fc2) + LN(norm2) + residual, in/out = d_out ---------
__global__ void __launch_bounds__(256) k_mlp(
    const float* __restrict__ w1, const float* __restrict__ b1f, const float* __restrict__ w2,
    const float* __restrict__ b2f, const float* __restrict__ n2w, const float* __restrict__ n2b,
    float* __restrict__ out) {
    const int tid = threadIdx.x;
    const int gt0 = blockIdx.x * 16;

    __shared__ __align__(16) float Xr[16][128];
    __shared__ __align__(16) float Wl[16][512];
    __shared__ __align__(16) float Hl[16][512];

#pragma unroll
    for (int q = 0; q < 2; ++q) {
        int lin = tid + 256 * q;
        int t = lin >> 5, f4i = lin & 31;
        *(float4*)&Xr[t][f4i * 4] = *(const float4*)(out + (gt0 + t) * 128 + f4i * 4);
    }

    // fc1: 16 tokens x 512 cols, K=128
    const int tx = tid & 63, ty = tid >> 6;  // ty 0..3
    float acc[4][8];
#pragma unroll
    for (int i = 0; i < 4; ++i)
#pragma unroll
        for (int j = 0; j < 8; ++j) acc[i][j] = 0.f;

    for (int kc = 0; kc < 8; ++kc) {
        __syncthreads();
#pragma unroll
        for (int q = 0; q < 8; ++q) {
            int lin = tid + 256 * q;  // 0..2047
            int oc = lin >> 2, f4i = lin & 3;
            float4 wv = *(const float4*)(w1 + oc * 128 + kc * 16 + f4i * 4);
            Wl[f4i * 4 + 0][oc] = wv.x;
            Wl[f4i * 4 + 1][oc] = wv.y;
            Wl[f4i * 4 + 2][oc] = wv.z;
            Wl[f4i * 4 + 3][oc] = wv.w;
        }
        __syncthreads();
#pragma unroll
        for (int k4 = 0; k4 < 4; ++k4) {
            float4 xv[4];
#pragma unroll
            for (int ri = 0; ri < 4; ++ri)
                xv[ri] = *(const float4*)&Xr[ty + 4 * ri][kc * 16 + k4 * 4];
#pragma unroll
            for (int j = 0; j < 4; ++j) {
                float wv[8];
#pragma unroll
                for (int ci = 0; ci < 8; ++ci) wv[ci] = Wl[k4 * 4 + j][tx + 64 * ci];
#pragma unroll
                for (int ri = 0; ri < 4; ++ri) {
                    float xval = (j == 0) ? xv[ri].x : (j == 1) ? xv[ri].y : (j == 2) ? xv[ri].z : xv[ri].w;
#pragma unroll
                    for (int ci = 0; ci < 8; ++ci) acc[ri][ci] += xval * wv[ci];
                }
            }
        }
    }
    // gelu (tanh approx, jax default) -> Hl
#pragma unroll
    for (int ri = 0; ri < 4; ++ri) {
        int t = ty + 4 * ri;
#pragma unroll
        for (int ci = 0; ci < 8; ++ci) {
            int col = tx + 64 * ci;
            float v = acc[ri][ci] + b1f[col];
            float g = 0.5f * v * (1.0f + tanhf(0.7978845608028654f * (v + 0.044715f * v * v * v)));
            Hl[t][col] = g;
        }
    }

    // fc2: 16 tokens x 128 cols, K=512
    const int tx2 = tid & 31, ty2 = tid >> 5;  // ty2 0..7
    float acc2[2][4];
#pragma unroll
    for (int i = 0; i < 2; ++i)
#pragma unroll
        for (int j = 0; j < 4; ++j) acc2[i][j] = 0.f;

    for (int kc = 0; kc < 32; ++kc) {
        __syncthreads();  // also guards Hl writes before first read
#pragma unroll
        for (int q = 0; q < 2; ++q) {
            int lin = tid + 256 * q;  // 0..511
            int oc = lin >> 2, f4i = lin & 3;
            float4 wv = *(const float4*)(w2 + oc * 512 + kc * 16 + f4i * 4);
            Wl[f4i * 4 + 0][oc] = wv.x;
            Wl[f4i * 4 + 1][oc] = wv.y;
            Wl[f4i * 4 + 2][oc] = wv.z;
            Wl[f4i * 4 + 3][oc] = wv.w;
        }
        __syncthreads();
#pragma unroll
        for (int k4 = 0; k4 < 4; ++k4) {
            float4 hv[2];
            hv[0] = *(const float4*)&Hl[ty2][kc * 16 + k4 * 4];
            hv[1] = *(const float4*)&Hl[ty2 + 8][kc * 16 + k4 * 4];
#pragma unroll
            for (int j = 0; j < 4; ++j) {
                float wv[4];
#pragma unroll
                for (int ci = 0; ci < 4; ++ci) wv[ci] = Wl[k4 * 4 + j][tx2 + 32 * ci];
#pragma unroll
                for (int ri = 0; ri < 2; ++ri) {
                    float hval = (j == 0) ? hv[ri].x : (j == 1) ? hv[ri].y : (j == 2) ? hv[ri].z : hv[ri].w;
#pragma unroll
                    for (int ci = 0; ci < 4; ++ci) acc2[ri][ci] += hval * wv[ci];
                }
            }
        }
    }

#pragma unroll
    for (int ri = 0; ri < 2; ++ri) {
        int t = ty2 + 8 * ri;
        float y[4];
        float s = 0.f, ssq = 0.f;
#pragma unroll
        for (int ci = 0; ci < 4; ++ci) {
            y[ci] = acc2[ri][ci] + b2f[tx2 + 32 * ci];
            s += y[ci];
            ssq += y[ci] * y[ci];
        }
#pragma unroll
        for (int m = 1; m < 32; m <<= 1) {
            s += __shfl_xor(s, m);
            ssq += __shfl_xor(ssq, m);
        }
        float mean = s * (1.0f / 128.0f);
        float var = ssq * (1.0f / 128.0f) - mean * mean;
        float rstd = rsqrtf(var + 1e-5f);
#pragma unroll
        for (int ci = 0; ci < 4; ++ci) {
            int col = tx2 + 32 * ci;
            float ln = (y[ci] - mean) * rstd * n2w[col] + n2b[col];
            out[(gt0 + t) * 128 + col] = Xr[t][col] + ln;
        }
    }
}

extern "C" void kernel_launch(void* const* d_in, const int* in_sizes, int n_in, void* d_out,
                              int out_size, void* d_ws, size_t ws_size, hipStream_t stream) {
    const float* x   = (const float*)d_in[0];
    const float* n1w = (const float*)d_in[1];
    const float* n1b = (const float*)d_in[2];
    const float* qw  = (const float*)d_in[3];
    const float* qb  = (const float*)d_in[4];
    const float* ls  = (const float*)d_in[5];
    const float* cw1 = (const float*)d_in[6];
    const float* cb1 = (const float*)d_in[7];
    const float* cw2 = (const float*)d_in[8];
    const float* pw  = (const float*)d_in[9];
    const float* pb  = (const float*)d_in[10];
    const float* n2w = (const float*)d_in[11];
    const float* n2b = (const float*)d_in[12];
    const float* w1  = (const float*)d_in[13];
    const float* b1f = (const float*)d_in[14];
    const float* w2  = (const float*)d_in[15];
    const float* b2f = (const float*)d_in[16];
    float* out = (float*)d_out;

    float* ws = (float*)d_ws;
    float* BT = ws;                 // 13500 floats (padded 13504)
    float* Qp = ws + 13504;         // 64*4*512*32 = 4194304
    float* Kp = Qp + 4194304;
    float* Vp = Kp + 4194304;
    float* AO = Vp + 4194304;       // 32768*128

    k_bias_table<<<3375, 128, 0, stream>>>(cw1, cb1, cw2, BT);
    k_qkv<<<dim3(8, 64, 3), 256, 0, stream>>>(x, qw, qb, ls, Qp, Kp, Vp);
    k_attn<<<dim3(32, 4, 64), 256, 0, stream>>>(Qp, Kp, Vp, BT, AO);
    k_proj_ln<<<dim3(8, 64), 256, 0, stream>>>(AO, pw, pb, n1w, n1b, x, out);
    k_mlp<<<2048, 256, 0, stream>>>(w1, b1f, w2, b2f, n2w, n2b, out);
}

// Round 2
// 440.717 us; speedup vs baseline: 2.1472x; 2.1472x over previous
//
#include <hip/hip_runtime.h>
#include <math.h>

// SwinV2-3D block: RES=32, WS=8, SHIFT=4, NH=4, DIM=128, windows=64, N=512/window.
// Round 2: bf16-MFMA flash attention (k_attn); k_qkv emits bf16 Q,K and bf16 V^T.

typedef short bf16x8 __attribute__((ext_vector_type(8)));
typedef float f32x4 __attribute__((ext_vector_type(4)));

__device__ __forceinline__ int regionOf(int wb, int a) {
    // shifted-coord region along one axis: 0 if coord<24, 1 if 24<=coord<28, 2 if >=28
    return (wb < 3) ? 0 : ((a < 4) ? 1 : 2);
}

__device__ __forceinline__ unsigned short f2bf(float f) {
    unsigned int u = __float_as_uint(f);
    u += 0x7fffu + ((u >> 16) & 1u);   // RNE (inputs are finite, no NaN handling needed)
    return (unsigned short)(u >> 16);
}

// ---------------- K0: CPB bias table: BT[3375][4] = 16*sigmoid(MLP(ctab)) ----------------
__global__ void k_bias_table(const float* __restrict__ w1, const float* __restrict__ b1,
                             const float* __restrict__ w2, float* __restrict__ BT) {
    int e = blockIdx.x;                       // 0..3374
    int id = e / 225, rem = e % 225, ih = rem / 15, iw = rem % 15;
    float ct[3];
    int ids[3] = {id, ih, iw};
#pragma unroll
    for (int a = 0; a < 3; ++a) {
        float r = (float)(ids[a] - 7) * (8.0f / 7.0f);
        float s = (r > 0.f) ? 1.f : ((r < 0.f) ? -1.f : 0.f);
        ct[a] = s * log2f(fabsf(r) + 1.0f) * (1.0f / 3.0f);   // /log2(8)
    }
    int t = threadIdx.x;                      // 128 threads
    float acc[4] = {0.f, 0.f, 0.f, 0.f};
    for (int j = t; j < 512; j += 128) {
        float hv = ct[0] * w1[j * 3 + 0] + ct[1] * w1[j * 3 + 1] + ct[2] * w1[j * 3 + 2] + b1[j];
        hv = fmaxf(hv, 0.f);
#pragma unroll
        for (int h = 0; h < 4; ++h) acc[h] += hv * w2[h * 512 + j];
    }
    __shared__ float red[4][128];
#pragma unroll
    for (int h = 0; h < 4; ++h) red[h][t] = acc[h];
    __syncthreads();
    if (t < 4) {
        float s = 0.f;
        for (int i = 0; i < 128; ++i) s += red[t][i];
        BT[e * 4 + t] = 16.0f / (1.0f + expf(-s));
    }
}

// ---------------- K0b: expand bias to BIAS4[h][m][n] (4 x 512 x 512 fp32) ----------------
__global__ void k_bias_expand(const float* __restrict__ BT, float* __restrict__ B4) {
    int idx = blockIdx.x * 256 + threadIdx.x;   // 262144
    int m = idx >> 9, n = idx & 511;
    int an = n >> 6, bn = (n >> 3) & 7, cn = n & 7;
    int am = m >> 6, bm = (m >> 3) & 7, cm = m & 7;
    int ridx = ((an - am + 7) * 15 + (bn - bm + 7)) * 15 + (cn - cm + 7);
    float4 bv = *(const float4*)(BT + ridx * 4);
    B4[(size_t)(0 * 512 + m) * 512 + n] = bv.x;
    B4[(size_t)(1 * 512 + m) * 512 + n] = bv.y;
    B4[(size_t)(2 * 512 + m) * 512 + n] = bv.z;
    B4[(size_t)(3 * 512 + m) * 512 + n] = bv.w;
}

// ---------------- K0c: per-(window,token) mask region class, CNT[w][n] uint8 -------------
__global__ void k_cnt(unsigned char* __restrict__ CNT) {
    int idx = blockIdx.x * 256 + threadIdx.x;   // 32768
    int w = idx >> 9, n = idx & 511;
    int wd = w >> 4, wh = (w >> 2) & 3, ww = w & 3;
    int a = n >> 6, b = (n >> 3) & 7, c = n & 7;
    CNT[idx] = (unsigned char)(regionOf(wd, a) * 9 + regionOf(wh, b) * 3 + regionOf(ww, c));
}

// ---------------- K1: roll+window gather + QKV GEMM + cosine norm -> bf16 Q,K,V^T --------
// grid (8 token-tiles, 64 windows, 3 slabs {q,k,v}), block 256
__global__ void __launch_bounds__(256) k_qkv(
    const float* __restrict__ x, const float* __restrict__ qw, const float* __restrict__ qb,
    const float* __restrict__ ls, unsigned short* __restrict__ Qb,
    unsigned short* __restrict__ Kb, unsigned short* __restrict__ Vt) {
    const int tile = blockIdx.x;
    const int w = blockIdx.y;
    const int slab = blockIdx.z;
    const int tid = threadIdx.x;
    const int tx = tid & 31, ty = tid >> 5;
    const int wd = w >> 4, wh = (w >> 2) & 3, ww = w & 3;

    __shared__ __align__(16) float As[64][128];
    __shared__ __align__(16) float Wl[32][128];

    // stage A tile (64 tokens x 128 ch) with shift+window gather
#pragma unroll
    for (int q = 0; q < 8; ++q) {
        int lin = tid + 256 * q;
        int r = lin >> 5, f4i = lin & 31;
        int n = tile * 64 + r;
        int a = n >> 6, b = (n >> 3) & 7, c = n & 7;
        int od = (wd * 8 + a + 4) & 31, oh = (wh * 8 + b + 4) & 31, ow = (ww * 8 + c + 4) & 31;
        const float4* src = (const float4*)(x + ((od * 32 + oh) * 32 + ow) * 128);
        *(float4*)&As[r][f4i * 4] = src[f4i];
    }

    float acc[8][4];
#pragma unroll
    for (int i = 0; i < 8; ++i)
#pragma unroll
        for (int j = 0; j < 4; ++j) acc[i][j] = 0.f;

    const int slabbase = slab * 128;
    for (int kc = 0; kc < 4; ++kc) {
        __syncthreads();
#pragma unroll
        for (int q = 0; q < 4; ++q) {
            int lin = tid + 256 * q;          // 0..1023
            int col = lin >> 3, f4i = lin & 7;
            float4 wv = *(const float4*)(qw + (slabbase + col) * 128 + kc * 32 + f4i * 4);
            Wl[f4i * 4 + 0][col] = wv.x;
            Wl[f4i * 4 + 1][col] = wv.y;
            Wl[f4i * 4 + 2][col] = wv.z;
            Wl[f4i * 4 + 3][col] = wv.w;
        }
        __syncthreads();
#pragma unroll
        for (int k4 = 0; k4 < 8; ++k4) {
            float4 av[8];
#pragma unroll
            for (int ri = 0; ri < 8; ++ri)
                av[ri] = *(const float4*)&As[ty + 8 * ri][kc * 32 + k4 * 4];
#pragma unroll
            for (int j = 0; j < 4; ++j) {
                float wv[4];
#pragma unroll
                for (int ci = 0; ci < 4; ++ci) wv[ci] = Wl[k4 * 4 + j][tx + 32 * ci];
#pragma unroll
                for (int ri = 0; ri < 8; ++ri) {
                    float aval = (j == 0) ? av[ri].x : (j == 1) ? av[ri].y : (j == 2) ? av[ri].z : av[ri].w;
#pragma unroll
                    for (int ci = 0; ci < 4; ++ci) acc[ri][ci] += aval * wv[ci];
                }
            }
        }
    }

    float scale[4];
    if (slab == 0) {
#pragma unroll
        for (int ci = 0; ci < 4; ++ci) scale[ci] = expf(fminf(ls[ci], 4.6051701859880914f));
    }
#pragma unroll
    for (int ri = 0; ri < 8; ++ri) {
        int r = ty + 8 * ri;
        int n = tile * 64 + r;
#pragma unroll
        for (int ci = 0; ci < 4; ++ci) {
            float v = acc[ri][ci] + qb[slabbase + tx + 32 * ci];
            if (slab < 2) {  // cosine normalization for q,k (head=ci, d=tx)
                float ss = v * v;
#pragma unroll
                for (int m = 1; m < 32; m <<= 1) ss += __shfl_xor(ss, m);
                v = v / (sqrtf(ss) + 1e-12f);
                if (slab == 0) v *= scale[ci];
                unsigned short* qk = (slab == 0) ? Qb : Kb;
                qk[((size_t)(w * 4 + ci) * 512 + n) * 32 + tx] = f2bf(v);
            } else {
                // V^T: [wh][d=32][n=512]
                Vt[((size_t)(w * 4 + ci) * 32 + tx) * 512 + n] = f2bf(v);
            }
        }
    }
}

// ---------------- K2: bf16-MFMA flash attention ----------------
// grid (8 q-octs of 64 rows, 4 heads, 64 windows), block 256 = 4 waves, wave = 16 q-rows.
// S^T = mfma(K_tile, Q^T): lane owns q = lane&15; online softmax over 8 chunks of 64 m.
// No __syncthreads: all LDS traffic is wave-private (P round-trip + padded pitch).
__global__ void __launch_bounds__(256) k_attn(
    const unsigned short* __restrict__ Qb, const unsigned short* __restrict__ Kb,
    const unsigned short* __restrict__ Vt, const float* __restrict__ B4,
    const unsigned char* __restrict__ CNT, float* __restrict__ AO) {
    const int qoct = blockIdx.x;  // 0..7
    const int h = blockIdx.y;     // 0..3
    const int w = blockIdx.z;     // 0..63
    const int tid = threadIdx.x;
    const int wv = tid >> 6;
    const int lane = tid & 63;
    const int qL = lane & 15;     // q (QK-C col / PV-A row / V-B col d)
    const int g = lane >> 4;      // k-group

    __shared__ __align__(16) unsigned short Pbuf[4][16][72];  // per-wave P tile, pitch-padded

    const int q0 = qoct * 64 + wv * 16;
    const int wh4 = w * 4 + h;
    const size_t qk_base = (size_t)wh4 * 512 * 32;
    const size_t vt_base = (size_t)wh4 * 32 * 512;

    // Q B-fragment: lane holds col q=lane&15, k = d = 8g..8g+7 -> Q[q][8g..] contiguous
    bf16x8 bQ = *(const bf16x8*)(Qb + qk_base + (size_t)(q0 + qL) * 32 + 8 * g);

    const int cq = CNT[w * 512 + q0 + qL];
    const float* Bh = B4 + (size_t)h * 512 * 512;
    const unsigned char* Cw = CNT + w * 512;
    unsigned short* prow = &Pbuf[wv][qL][0];

    float m_run = -1e30f, l_run = 0.f;
    f32x4 o0 = {0.f, 0.f, 0.f, 0.f}, o1 = {0.f, 0.f, 0.f, 0.f};

    for (int c = 0; c < 8; ++c) {
        const int m0 = c * 64;
        f32x4 st[4];
        // S^T tiles: A = K[16m x 32d] (lane row m=lane&15, k=d=8g+e), B = bQ
#pragma unroll
        for (int t = 0; t < 4; ++t) {
            bf16x8 aK = *(const bf16x8*)(Kb + qk_base + (size_t)(m0 + t * 16 + qL) * 32 + 8 * g);
            st[t] = __builtin_amdgcn_mfma_f32_16x16x32_bf16(
                aK, bQ, (f32x4){0.f, 0.f, 0.f, 0.f}, 0, 0, 0);
        }
        // + bias + mask; chunk max (lane holds m = m0 + t*16 + 4g + r for its q)
        float cmax = -1e30f;
#pragma unroll
        for (int t = 0; t < 4; ++t) {
            int mb = m0 + t * 16 + 4 * g;
#pragma unroll
            for (int r = 0; r < 4; ++r) {
                float sv = st[t][r] + Bh[(size_t)(mb + r) * 512 + q0 + qL];
                sv += (Cw[mb + r] == cq) ? 0.f : -100.f;
                st[t][r] = sv;
                cmax = fmaxf(cmax, sv);
            }
        }
        cmax = fmaxf(cmax, __shfl_xor(cmax, 16));
        cmax = fmaxf(cmax, __shfl_xor(cmax, 32));
        float mnew = fmaxf(m_run, cmax);
        float corr = __expf(m_run - mnew);
        float csum = 0.f;
#pragma unroll
        for (int t = 0; t < 4; ++t) {
#pragma unroll
            for (int r = 0; r < 4; ++r) {
                float p = __expf(st[t][r] - mnew);
                st[t][r] = p;
                csum += p;
            }
        }
        csum += __shfl_xor(csum, 16);
        csum += __shfl_xor(csum, 32);
        l_run = l_run * corr + csum;
        m_run = mnew;
        // rescale O: row q' = 4g+r needs corr owned by lanes with lane&15 == q'
#pragma unroll
        for (int r = 0; r < 4; ++r) {
            float cr = __shfl(corr, 4 * g + r, 64);
            o0[r] *= cr;
            o1[r] *= cr;
        }
        // P -> bf16 -> wave-private LDS (elem index == m - m0)
#pragma unroll
        for (int t = 0; t < 4; ++t) {
            unsigned int lo = (unsigned int)f2bf(st[t][0]) | ((unsigned int)f2bf(st[t][1]) << 16);
            unsigned int hi = (unsigned int)f2bf(st[t][2]) | ((unsigned int)f2bf(st[t][3]) << 16);
            *(uint2*)(prow + t * 16 + 4 * g) = make_uint2(lo, hi);
        }
        // PV: A = P[16q x 32m] from Pbuf, B = V[32m x 16d] from Vt (both 16B reads)
#pragma unroll
        for (int s = 0; s < 2; ++s) {
            bf16x8 pa = *(const bf16x8*)(prow + s * 32 + 8 * g);
            bf16x8 bv0 = *(const bf16x8*)(Vt + vt_base + (size_t)qL * 512 + m0 + s * 32 + 8 * g);
            bf16x8 bv1 = *(const bf16x8*)(Vt + vt_base + (size_t)(16 + qL) * 512 + m0 + s * 32 + 8 * g);
            o0 = __builtin_amdgcn_mfma_f32_16x16x32_bf16(pa, bv0, o0, 0, 0, 0);
            o1 = __builtin_amdgcn_mfma_f32_16x16x32_bf16(pa, bv1, o1, 0, 0, 0);
        }
    }
    // epilogue: divide by row-sum; lane holds (d = qL [+16], q = 4g+r)
    float linv = 1.0f / l_run;
#pragma unroll
    for (int r = 0; r < 4; ++r) {
        float lr = __shfl(linv, 4 * g + r, 64);
        int q = q0 + 4 * g + r;
        AO[(size_t)(w * 512 + q) * 128 + h * 32 + qL] = o0[r] * lr;
        AO[(size_t)(w * 512 + q) * 128 + h * 32 + 16 + qL] = o1[r] * lr;
    }
}

// ---------------- K3: proj + LN(norm1) + residual, scatter to spatial ----------------
__global__ void __launch_bounds__(256) k_proj_ln(
    const float* __restrict__ AO, const float* __restrict__ pw, const float* __restrict__ pb,
    const float* __restrict__ n1w, const float* __restrict__ n1b, const float* __restrict__ x,
    float* __restrict__ out) {
    const int tile = blockIdx.x;  // 0..7
    const int w = blockIdx.y;     // 0..63
    const int tid = threadIdx.x;
    const int tx = tid & 31, ty = tid >> 5;
    const int wd = w >> 4, wh = (w >> 2) & 3, ww = w & 3;

    __shared__ __align__(16) float As[64][128];
    __shared__ __align__(16) float Wl[32][128];

#pragma unroll
    for (int q = 0; q < 8; ++q) {
        int lin = tid + 256 * q;
        int r = lin >> 5, f4i = lin & 31;
        *(float4*)&As[r][f4i * 4] =
            *(const float4*)(AO + (w * 512 + tile * 64 + r) * 128 + f4i * 4);
    }

    float acc[8][4];
#pragma unroll
    for (int i = 0; i < 8; ++i)
#pragma unroll
        for (int j = 0; j < 4; ++j) acc[i][j] = 0.f;

    for (int kc = 0; kc < 4; ++kc) {
        __syncthreads();
#pragma unroll
        for (int q = 0; q < 4; ++q) {
            int lin = tid + 256 * q;
            int col = lin >> 3, f4i = lin & 7;
            float4 wv = *(const float4*)(pw + col * 128 + kc * 32 + f4i * 4);
            Wl[f4i * 4 + 0][col] = wv.x;
            Wl[f4i * 4 + 1][col] = wv.y;
            Wl[f4i * 4 + 2][col] = wv.z;
            Wl[f4i * 4 + 3][col] = wv.w;
        }
        __syncthreads();
#pragma unroll
        for (int k4 = 0; k4 < 8; ++k4) {
            float4 av[8];
#pragma unroll
            for (int ri = 0; ri < 8; ++ri)
                av[ri] = *(const float4*)&As[ty + 8 * ri][kc * 32 + k4 * 4];
#pragma unroll
            for (int j = 0; j < 4; ++j) {
                float wv[4];
#pragma unroll
                for (int ci = 0; ci < 4; ++ci) wv[ci] = Wl[k4 * 4 + j][tx + 32 * ci];
#pragma unroll
                for (int ri = 0; ri < 8; ++ri) {
                    float aval = (j == 0) ? av[ri].x : (j == 1) ? av[ri].y : (j == 2) ? av[ri].z : av[ri].w;
#pragma unroll
                    for (int ci = 0; ci < 4; ++ci) acc[ri][ci] += aval * wv[ci];
                }
            }
        }
    }

#pragma unroll
    for (int ri = 0; ri < 8; ++ri) {
        int r = ty + 8 * ri;
        int n = tile * 64 + r;
        float y[4];
        float s = 0.f, ssq = 0.f;
#pragma unroll
        for (int ci = 0; ci < 4; ++ci) {
            y[ci] = acc[ri][ci] + pb[tx + 32 * ci];
            s += y[ci];
            ssq += y[ci] * y[ci];
        }
#pragma unroll
        for (int m = 1; m < 32; m <<= 1) {
            s += __shfl_xor(s, m);
            ssq += __shfl_xor(ssq, m);
        }
        float mean = s * (1.0f / 128.0f);
        float var = ssq * (1.0f / 128.0f) - mean * mean;
        float rstd = rsqrtf(var + 1e-5f);
        int a = n >> 6, b = (n >> 3) & 7, c = n & 7;
        int od = (wd * 8 + a + 4) & 31, oh = (wh * 8 + b + 4) & 31, ow = (ww * 8 + c + 4) & 31;
        int off = ((od * 32 + oh) * 32 + ow) * 128;
#pragma unroll
        for (int ci = 0; ci < 4; ++ci) {
            int col = tx + 32 * ci;
            float ln = (y[ci] - mean) * rstd * n1w[col] + n1b[col];
            out[off + col] = x[off + col] + ln;
        }
    }
}

// ---------------- K4: MLP (fc1+gelu+fc2) + LN(norm2) + residual, in/out = d_out ---------
__global__ void __launch_bounds__(256) k_mlp(
    const float* __restrict__ w1, const float* __restrict__ b1f, const float* __restrict__ w2,
    const float* __restrict__ b2f, const float* __restrict__ n2w, const float* __restrict__ n2b,
    float* __restrict__ out) {
    const int tid = threadIdx.x;
    const int gt0 = blockIdx.x * 16;

    __shared__ __align__(16) float Xr[16][128];
    __shared__ __align__(16) float Wl[16][512];
    __shared__ __align__(16) float Hl[16][512];

#pragma unroll
    for (int q = 0; q < 2; ++q) {
        int lin = tid + 256 * q;
        int t = lin >> 5, f4i = lin & 31;
        *(float4*)&Xr[t][f4i * 4] = *(const float4*)(out + (gt0 + t) * 128 + f4i * 4);
    }

    // fc1: 16 tokens x 512 cols, K=128
    const int tx = tid & 63, ty = tid >> 6;  // ty 0..3
    float acc[4][8];
#pragma unroll
    for (int i = 0; i < 4; ++i)
#pragma unroll
        for (int j = 0; j < 8; ++j) acc[i][j] = 0.f;

    for (int kc = 0; kc < 8; ++kc) {
        __syncthreads();
#pragma unroll
        for (int q = 0; q < 8; ++q) {
            int lin = tid + 256 * q;  // 0..2047
            int oc = lin >> 2, f4i = lin & 3;
            float4 wv = *(const float4*)(w1 + oc * 128 + kc * 16 + f4i * 4);
            Wl[f4i * 4 + 0][oc] = wv.x;
            Wl[f4i * 4 + 1][oc] = wv.y;
            Wl[f4i * 4 + 2][oc] = wv.z;
            Wl[f4i * 4 + 3][oc] = wv.w;
        }
        __syncthreads();
#pragma unroll
        for (int k4 = 0; k4 < 4; ++k4) {
            float4 xv[4];
#pragma unroll
            for (int ri = 0; ri < 4; ++ri)
                xv[ri] = *(const float4*)&Xr[ty + 4 * ri][kc * 16 + k4 * 4];
#pragma unroll
            for (int j = 0; j < 4; ++j) {
                float wv[8];
#pragma unroll
                for (int ci = 0; ci < 8; ++ci) wv[ci] = Wl[k4 * 4 + j][tx + 64 * ci];
#pragma unroll
                for (int ri = 0; ri < 4; ++ri) {
                    float xval = (j == 0) ? xv[ri].x : (j == 1) ? xv[ri].y : (j == 2) ? xv[ri].z : xv[ri].w;
#pragma unroll
                    for (int ci = 0; ci < 8; ++ci) acc[ri][ci] += xval * wv[ci];
                }
            }
        }
    }
    // gelu (tanh approx, jax default) -> Hl
#pragma unroll
    for (int ri = 0; ri < 4; ++ri) {
        int t = ty + 4 * ri;
#pragma unroll
        for (int ci = 0; ci < 8; ++ci) {
            int col = tx + 64 * ci;
            float v = acc[ri][ci] + b1f[col];
            float g = 0.5f * v * (1.0f + tanhf(0.7978845608028654f * (v + 0.044715f * v * v * v)));
            Hl[t][col] = g;
        }
    }

    // fc2: 16 tokens x 128 cols, K=512
    const int tx2 = tid & 31, ty2 = tid >> 5;  // ty2 0..7
    float acc2[2][4];
#pragma unroll
    for (int i = 0; i < 2; ++i)
#pragma unroll
        for (int j = 0; j < 4; ++j) acc2[i][j] = 0.f;

    for (int kc = 0; kc < 32; ++kc) {
        __syncthreads();  // also guards Hl writes before first read
#pragma unroll
        for (int q = 0; q < 2; ++q) {
            int lin = tid + 256 * q;  // 0..511
            int oc = lin >> 2, f4i = lin & 3;
            float4 wv = *(const float4*)(w2 + oc * 512 + kc * 16 + f4i * 4);
            Wl[f4i * 4 + 0][oc] = wv.x;
            Wl[f4i * 4 + 1][oc] = wv.y;
            Wl[f4i * 4 + 2][oc] = wv.z;
            Wl[f4i * 4 + 3][oc] = wv.w;
        }
        __syncthreads();
#pragma unroll
        for (int k4 = 0; k4 < 4; ++k4) {
            float4 hv[2];
            hv[0] = *(const float4*)&Hl[ty2][kc * 16 + k4 * 4];
            hv[1] = *(const float4*)&Hl[ty2 + 8][kc * 16 + k4 * 4];
#pragma unroll
            for (int j = 0; j < 4; ++j) {
                float wv[4];
#pragma unroll
                for (int ci = 0; ci < 4; ++ci) wv[ci] = Wl[k4 * 4 + j][tx2 + 32 * ci];
#pragma unroll
                for (int ri = 0; ri < 2; ++ri) {
                    float hval = (j == 0) ? hv[ri].x : (j == 1) ? hv[ri].y : (j == 2) ? hv[ri].z : hv[ri].w;
#pragma unroll
                    for (int ci = 0; ci < 4; ++ci) acc2[ri][ci] += hval * wv[ci];
                }
            }
        }
    }

#pragma unroll
    for (int ri = 0; ri < 2; ++ri) {
        int t = ty2 + 8 * ri;
        float y[4];
        float s = 0.f, ssq = 0.f;
#pragma unroll
        for (int ci = 0; ci < 4; ++ci) {
            y[ci] = acc2[ri][ci] + b2f[tx2 + 32 * ci];
            s += y[ci];
            ssq += y[ci] * y[ci];
        }
#pragma unroll
        for (int m = 1; m < 32; m <<= 1) {
            s += __shfl_xor(s, m);
            ssq += __shfl_xor(ssq, m);
        }
        float mean = s * (1.0f / 128.0f);
        float var = ssq * (1.0f / 128.0f) - mean * mean;
        float rstd = rsqrtf(var + 1e-5f);
#pragma unroll
        for (int ci = 0; ci < 4; ++ci) {
            int col = tx2 + 32 * ci;
            float ln = (y[ci] - mean) * rstd * n2w[col] + n2b[col];
            out[(gt0 + t) * 128 + col] = Xr[t][col] + ln;
        }
    }
}

extern "C" void kernel_launch(void* const* d_in, const int* in_sizes, int n_in, void* d_out,
                              int out_size, void* d_ws, size_t ws_size, hipStream_t stream) {
    const float* x   = (const float*)d_in[0];
    const float* n1w = (const float*)d_in[1];
    const float* n1b = (const float*)d_in[2];
    const float* qw  = (const float*)d_in[3];
    const float* qb  = (const float*)d_in[4];
    const float* ls  = (const float*)d_in[5];
    const float* cw1 = (const float*)d_in[6];
    const float* cb1 = (const float*)d_in[7];
    const float* cw2 = (const float*)d_in[8];
    const float* pw  = (const float*)d_in[9];
    const float* pb  = (const float*)d_in[10];
    const float* n2w = (const float*)d_in[11];
    const float* n2b = (const float*)d_in[12];
    const float* w1  = (const float*)d_in[13];
    const float* b1f = (const float*)d_in[14];
    const float* w2  = (const float*)d_in[15];
    const float* b2f = (const float*)d_in[16];
    float* out = (float*)d_out;

    float* ws = (float*)d_ws;
    float* BT = ws;                                        // 13504 floats
    float* B4 = ws + 13504;                                // 1048576 floats (4x512x512)
    unsigned char* CNT8 = (unsigned char*)(ws + 1062080);  // 32768 bytes (8192 floats)
    unsigned short* Qb = (unsigned short*)(ws + 1070272);  // 4194304 ushort (2097152 floats)
    unsigned short* Kb = (unsigned short*)(ws + 3167424);
    unsigned short* Vt = (unsigned short*)(ws + 5264576);
    float* AO = ws + 7361728;                              // 4194304 floats

    k_bias_table<<<3375, 128, 0, stream>>>(cw1, cb1, cw2, BT);
    k_bias_expand<<<1024, 256, 0, stream>>>(BT, B4);
    k_cnt<<<128, 256, 0, stream>>>(CNT8);
    k_qkv<<<dim3(8, 64, 3), 256, 0, stream>>>(x, qw, qb, ls, Qb, Kb, Vt);
    k_attn<<<dim3(8, 4, 64), 256, 0, stream>>>(Qb, Kb, Vt, B4, CNT8, AO);
    k_proj_ln<<<dim3(8, 64), 256, 0, stream>>>(AO, pw, pb, n1w, n1b, x, out);
    k_mlp<<<2048, 256, 0, stream>>>(w1, b1f, w2, b2f, n2w, n2b, out);
}

// Round 3
// 265.127 us; speedup vs baseline: 3.5692x; 1.6623x over previous
//
#include <hip/hip_runtime.h>
#include <math.h>

// SwinV2-3D block: RES=32, WS=8, SHIFT=4, NH=4, DIM=128, windows=64, N=512/window.
// Round 3: bf16-MFMA MLP (k_mlp); k_proj_ln also emits bf16 Xb; weights pre-cast to bf16.

typedef short bf16x8 __attribute__((ext_vector_type(8)));
typedef float f32x4 __attribute__((ext_vector_type(4)));

__device__ __forceinline__ int regionOf(int wb, int a) {
    // shifted-coord region along one axis: 0 if coord<24, 1 if 24<=coord<28, 2 if >=28
    return (wb < 3) ? 0 : ((a < 4) ? 1 : 2);
}

__device__ __forceinline__ unsigned short f2bf(float f) {
    unsigned int u = __float_as_uint(f);
    u += 0x7fffu + ((u >> 16) & 1u);   // RNE (inputs are finite, no NaN handling needed)
    return (unsigned short)(u >> 16);
}

// ---------------- K0: CPB bias table: BT[3375][4] = 16*sigmoid(MLP(ctab)) ----------------
__global__ void k_bias_table(const float* __restrict__ w1, const float* __restrict__ b1,
                             const float* __restrict__ w2, float* __restrict__ BT) {
    int e = blockIdx.x;                       // 0..3374
    int id = e / 225, rem = e % 225, ih = rem / 15, iw = rem % 15;
    float ct[3];
    int ids[3] = {id, ih, iw};
#pragma unroll
    for (int a = 0; a < 3; ++a) {
        float r = (float)(ids[a] - 7) * (8.0f / 7.0f);
        float s = (r > 0.f) ? 1.f : ((r < 0.f) ? -1.f : 0.f);
        ct[a] = s * log2f(fabsf(r) + 1.0f) * (1.0f / 3.0f);   // /log2(8)
    }
    int t = threadIdx.x;                      // 128 threads
    float acc[4] = {0.f, 0.f, 0.f, 0.f};
    for (int j = t; j < 512; j += 128) {
        float hv = ct[0] * w1[j * 3 + 0] + ct[1] * w1[j * 3 + 1] + ct[2] * w1[j * 3 + 2] + b1[j];
        hv = fmaxf(hv, 0.f);
#pragma unroll
        for (int h = 0; h < 4; ++h) acc[h] += hv * w2[h * 512 + j];
    }
    __shared__ float red[4][128];
#pragma unroll
    for (int h = 0; h < 4; ++h) red[h][t] = acc[h];
    __syncthreads();
    if (t < 4) {
        float s = 0.f;
        for (int i = 0; i < 128; ++i) s += red[t][i];
        BT[e * 4 + t] = 16.0f / (1.0f + expf(-s));
    }
}

// ---------------- K0b: expand bias to BIAS4[h][m][n] (4 x 512 x 512 fp32) ----------------
__global__ void k_bias_expand(const float* __restrict__ BT, float* __restrict__ B4) {
    int idx = blockIdx.x * 256 + threadIdx.x;   // 262144
    int m = idx >> 9, n = idx & 511;
    int an = n >> 6, bn = (n >> 3) & 7, cn = n & 7;
    int am = m >> 6, bm = (m >> 3) & 7, cm = m & 7;
    int ridx = ((an - am + 7) * 15 + (bn - bm + 7)) * 15 + (cn - cm + 7);
    float4 bv = *(const float4*)(BT + ridx * 4);
    B4[(size_t)(0 * 512 + m) * 512 + n] = bv.x;
    B4[(size_t)(1 * 512 + m) * 512 + n] = bv.y;
    B4[(size_t)(2 * 512 + m) * 512 + n] = bv.z;
    B4[(size_t)(3 * 512 + m) * 512 + n] = bv.w;
}

// ---------------- K0c: per-(window,token) mask region class, CNT[w][n] uint8 -------------
__global__ void k_cnt(unsigned char* __restrict__ CNT) {
    int idx = blockIdx.x * 256 + threadIdx.x;   // 32768
    int w = idx >> 9, n = idx & 511;
    int wd = w >> 4, wh = (w >> 2) & 3, ww = w & 3;
    int a = n >> 6, b = (n >> 3) & 7, c = n & 7;
    CNT[idx] = (unsigned char)(regionOf(wd, a) * 9 + regionOf(wh, b) * 3 + regionOf(ww, c));
}

// ---------------- K0d: cast MLP weights to bf16 ----------------
__global__ void k_wcvt(const float* __restrict__ w1, const float* __restrict__ w2,
                       unsigned short* __restrict__ W1b, unsigned short* __restrict__ W2b) {
    int idx = blockIdx.x * 256 + threadIdx.x;   // 65536
    W1b[idx] = f2bf(w1[idx]);
    W2b[idx] = f2bf(w2[idx]);
}

// ---------------- K1: roll+window gather + QKV GEMM + cosine norm -> bf16 Q,K,V^T --------
// grid (8 token-tiles, 64 windows, 3 slabs {q,k,v}), block 256
__global__ void __launch_bounds__(256) k_qkv(
    const float* __restrict__ x, const float* __restrict__ qw, const float* __restrict__ qb,
    const float* __restrict__ ls, unsigned short* __restrict__ Qb,
    unsigned short* __restrict__ Kb, unsigned short* __restrict__ Vt) {
    const int tile = blockIdx.x;
    const int w = blockIdx.y;
    const int slab = blockIdx.z;
    const int tid = threadIdx.x;
    const int tx = tid & 31, ty = tid >> 5;
    const int wd = w >> 4, wh = (w >> 2) & 3, ww = w & 3;

    __shared__ __align__(16) float As[64][128];
    __shared__ __align__(16) float Wl[32][128];

    // stage A tile (64 tokens x 128 ch) with shift+window gather
#pragma unroll
    for (int q = 0; q < 8; ++q) {
        int lin = tid + 256 * q;
        int r = lin >> 5, f4i = lin & 31;
        int n = tile * 64 + r;
        int a = n >> 6, b = (n >> 3) & 7, c = n & 7;
        int od = (wd * 8 + a + 4) & 31, oh = (wh * 8 + b + 4) & 31, ow = (ww * 8 + c + 4) & 31;
        const float4* src = (const float4*)(x + ((od * 32 + oh) * 32 + ow) * 128);
        *(float4*)&As[r][f4i * 4] = src[f4i];
    }

    float acc[8][4];
#pragma unroll
    for (int i = 0; i < 8; ++i)
#pragma unroll
        for (int j = 0; j < 4; ++j) acc[i][j] = 0.f;

    const int slabbase = slab * 128;
    for (int kc = 0; kc < 4; ++kc) {
        __syncthreads();
#pragma unroll
        for (int q = 0; q < 4; ++q) {
            int lin = tid + 256 * q;          // 0..1023
            int col = lin >> 3, f4i = lin & 7;
            float4 wv = *(const float4*)(qw + (slabbase + col) * 128 + kc * 32 + f4i * 4);
            Wl[f4i * 4 + 0][col] = wv.x;
            Wl[f4i * 4 + 1][col] = wv.y;
            Wl[f4i * 4 + 2][col] = wv.z;
            Wl[f4i * 4 + 3][col] = wv.w;
        }
        __syncthreads();
#pragma unroll
        for (int k4 = 0; k4 < 8; ++k4) {
            float4 av[8];
#pragma unroll
            for (int ri = 0; ri < 8; ++ri)
                av[ri] = *(const float4*)&As[ty + 8 * ri][kc * 32 + k4 * 4];
#pragma unroll
            for (int j = 0; j < 4; ++j) {
                float wv[4];
#pragma unroll
                for (int ci = 0; ci < 4; ++ci) wv[ci] = Wl[k4 * 4 + j][tx + 32 * ci];
#pragma unroll
                for (int ri = 0; ri < 8; ++ri) {
                    float aval = (j == 0) ? av[ri].x : (j == 1) ? av[ri].y : (j == 2) ? av[ri].z : av[ri].w;
#pragma unroll
                    for (int ci = 0; ci < 4; ++ci) acc[ri][ci] += aval * wv[ci];
                }
            }
        }
    }

    float scale[4];
    if (slab == 0) {
#pragma unroll
        for (int ci = 0; ci < 4; ++ci) scale[ci] = expf(fminf(ls[ci], 4.6051701859880914f));
    }
#pragma unroll
    for (int ri = 0; ri < 8; ++ri) {
        int r = ty + 8 * ri;
        int n = tile * 64 + r;
#pragma unroll
        for (int ci = 0; ci < 4; ++ci) {
            float v = acc[ri][ci] + qb[slabbase + tx + 32 * ci];
            if (slab < 2) {  // cosine normalization for q,k (head=ci, d=tx)
                float ss = v * v;
#pragma unroll
                for (int m = 1; m < 32; m <<= 1) ss += __shfl_xor(ss, m);
                v = v / (sqrtf(ss) + 1e-12f);
                if (slab == 0) v *= scale[ci];
                unsigned short* qk = (slab == 0) ? Qb : Kb;
                qk[((size_t)(w * 4 + ci) * 512 + n) * 32 + tx] = f2bf(v);
            } else {
                // V^T: [wh][d=32][n=512]
                Vt[((size_t)(w * 4 + ci) * 32 + tx) * 512 + n] = f2bf(v);
            }
        }
    }
}

// ---------------- K2: bf16-MFMA flash attention ----------------
// grid (8 q-octs of 64 rows, 4 heads, 64 windows), block 256 = 4 waves, wave = 16 q-rows.
__global__ void __launch_bounds__(256) k_attn(
    const unsigned short* __restrict__ Qb, const unsigned short* __restrict__ Kb,
    const unsigned short* __restrict__ Vt, const float* __restrict__ B4,
    const unsigned char* __restrict__ CNT, float* __restrict__ AO) {
    const int qoct = blockIdx.x;  // 0..7
    const int h = blockIdx.y;     // 0..3
    const int w = blockIdx.z;     // 0..63
    const int tid = threadIdx.x;
    const int wv = tid >> 6;
    const int lane = tid & 63;
    const int qL = lane & 15;     // q (QK-C col / PV-A row / V-B col d)
    const int g = lane >> 4;      // k-group

    __shared__ __align__(16) unsigned short Pbuf[4][16][72];  // per-wave P tile, pitch-padded

    const int q0 = qoct * 64 + wv * 16;
    const int wh4 = w * 4 + h;
    const size_t qk_base = (size_t)wh4 * 512 * 32;
    const size_t vt_base = (size_t)wh4 * 32 * 512;

    // Q B-fragment: lane holds col q=lane&15, k = d = 8g..8g+7 -> Q[q][8g..] contiguous
    bf16x8 bQ = *(const bf16x8*)(Qb + qk_base + (size_t)(q0 + qL) * 32 + 8 * g);

    const int cq = CNT[w * 512 + q0 + qL];
    const float* Bh = B4 + (size_t)h * 512 * 512;
    const unsigned char* Cw = CNT + w * 512;
    unsigned short* prow = &Pbuf[wv][qL][0];

    float m_run = -1e30f, l_run = 0.f;
    f32x4 o0 = {0.f, 0.f, 0.f, 0.f}, o1 = {0.f, 0.f, 0.f, 0.f};

    for (int c = 0; c < 8; ++c) {
        const int m0 = c * 64;
        f32x4 st[4];
        // S^T tiles: A = K[16m x 32d] (lane row m=lane&15, k=d=8g+e), B = bQ
#pragma unroll
        for (int t = 0; t < 4; ++t) {
            bf16x8 aK = *(const bf16x8*)(Kb + qk_base + (size_t)(m0 + t * 16 + qL) * 32 + 8 * g);
            st[t] = __builtin_amdgcn_mfma_f32_16x16x32_bf16(
                aK, bQ, (f32x4){0.f, 0.f, 0.f, 0.f}, 0, 0, 0);
        }
        // + bias + mask; chunk max (lane holds m = m0 + t*16 + 4g + r for its q)
        float cmax = -1e30f;
#pragma unroll
        for (int t = 0; t < 4; ++t) {
            int mb = m0 + t * 16 + 4 * g;
#pragma unroll
            for (int r = 0; r < 4; ++r) {
                float sv = st[t][r] + Bh[(size_t)(mb + r) * 512 + q0 + qL];
                sv += (Cw[mb + r] == cq) ? 0.f : -100.f;
                st[t][r] = sv;
                cmax = fmaxf(cmax, sv);
            }
        }
        cmax = fmaxf(cmax, __shfl_xor(cmax, 16));
        cmax = fmaxf(cmax, __shfl_xor(cmax, 32));
        float mnew = fmaxf(m_run, cmax);
        float corr = __expf(m_run - mnew);
        float csum = 0.f;
#pragma unroll
        for (int t = 0; t < 4; ++t) {
#pragma unroll
            for (int r = 0; r < 4; ++r) {
                float p = __expf(st[t][r] - mnew);
                st[t][r] = p;
                csum += p;
            }
        }
        csum += __shfl_xor(csum, 16);
        csum += __shfl_xor(csum, 32);
        l_run = l_run * corr + csum;
        m_run = mnew;
        // rescale O: row q' = 4g+r needs corr owned by lanes with lane&15 == q'
#pragma unroll
        for (int r = 0; r < 4; ++r) {
            float cr = __shfl(corr, 4 * g + r, 64);
            o0[r] *= cr;
            o1[r] *= cr;
        }
        // P -> bf16 -> wave-private LDS (elem index == m - m0)
#pragma unroll
        for (int t = 0; t < 4; ++t) {
            unsigned int lo = (unsigned int)f2bf(st[t][0]) | ((unsigned int)f2bf(st[t][1]) << 16);
            unsigned int hi = (unsigned int)f2bf(st[t][2]) | ((unsigned int)f2bf(st[t][3]) << 16);
            *(uint2*)(prow + t * 16 + 4 * g) = make_uint2(lo, hi);
        }
        // PV: A = P[16q x 32m] from Pbuf, B = V[32m x 16d] from Vt (both 16B reads)
#pragma unroll
        for (int s = 0; s < 2; ++s) {
            bf16x8 pa = *(const bf16x8*)(prow + s * 32 + 8 * g);
            bf16x8 bv0 = *(const bf16x8*)(Vt + vt_base + (size_t)qL * 512 + m0 + s * 32 + 8 * g);
            bf16x8 bv1 = *(const bf16x8*)(Vt + vt_base + (size_t)(16 + qL) * 512 + m0 + s * 32 + 8 * g);
            o0 = __builtin_amdgcn_mfma_f32_16x16x32_bf16(pa, bv0, o0, 0, 0, 0);
            o1 = __builtin_amdgcn_mfma_f32_16x16x32_bf16(pa, bv1, o1, 0, 0, 0);
        }
    }
    // epilogue: divide by row-sum; lane holds (d = qL [+16], q = 4g+r)
    float linv = 1.0f / l_run;
#pragma unroll
    for (int r = 0; r < 4; ++r) {
        float lr = __shfl(linv, 4 * g + r, 64);
        int q = q0 + 4 * g + r;
        AO[(size_t)(w * 512 + q) * 128 + h * 32 + qL] = o0[r] * lr;
        AO[(size_t)(w * 512 + q) * 128 + h * 32 + 16 + qL] = o1[r] * lr;
    }
}

// ---------------- K3: proj + LN(norm1) + residual, scatter to spatial (+bf16 Xb) --------
__global__ void __launch_bounds__(256) k_proj_ln(
    const float* __restrict__ AO, const float* __restrict__ pw, const float* __restrict__ pb,
    const float* __restrict__ n1w, const float* __restrict__ n1b, const float* __restrict__ x,
    float* __restrict__ out, unsigned short* __restrict__ Xb) {
    const int tile = blockIdx.x;  // 0..7
    const int w = blockIdx.y;     // 0..63
    const int tid = threadIdx.x;
    const int tx = tid & 31, ty = tid >> 5;
    const int wd = w >> 4, wh = (w >> 2) & 3, ww = w & 3;

    __shared__ __align__(16) float As[64][128];
    __shared__ __align__(16) float Wl[32][128];

#pragma unroll
    for (int q = 0; q < 8; ++q) {
        int lin = tid + 256 * q;
        int r = lin >> 5, f4i = lin & 31;
        *(float4*)&As[r][f4i * 4] =
            *(const float4*)(AO + (w * 512 + tile * 64 + r) * 128 + f4i * 4);
    }

    float acc[8][4];
#pragma unroll
    for (int i = 0; i < 8; ++i)
#pragma unroll
        for (int j = 0; j < 4; ++j) acc[i][j] = 0.f;

    for (int kc = 0; kc < 4; ++kc) {
        __syncthreads();
#pragma unroll
        for (int q = 0; q < 4; ++q) {
            int lin = tid + 256 * q;
            int col = lin >> 3, f4i = lin & 7;
            float4 wv = *(const float4*)(pw + col * 128 + kc * 32 + f4i * 4);
            Wl[f4i * 4 + 0][col] = wv.x;
            Wl[f4i * 4 + 1][col] = wv.y;
            Wl[f4i * 4 + 2][col] = wv.z;
            Wl[f4i * 4 + 3][col] = wv.w;
        }
        __syncthreads();
#pragma unroll
        for (int k4 = 0; k4 < 8; ++k4) {
            float4 av[8];
#pragma unroll
            for (int ri = 0; ri < 8; ++ri)
                av[ri] = *(const float4*)&As[ty + 8 * ri][kc * 32 + k4 * 4];
#pragma unroll
            for (int j = 0; j < 4; ++j) {
                float wv[4];
#pragma unroll
                for (int ci = 0; ci < 4; ++ci) wv[ci] = Wl[k4 * 4 + j][tx + 32 * ci];
#pragma unroll
                for (int ri = 0; ri < 8; ++ri) {
                    float aval = (j == 0) ? av[ri].x : (j == 1) ? av[ri].y : (j == 2) ? av[ri].z : av[ri].w;
#pragma unroll
                    for (int ci = 0; ci < 4; ++ci) acc[ri][ci] += aval * wv[ci];
                }
            }
        }
    }

#pragma unroll
    for (int ri = 0; ri < 8; ++ri) {
        int r = ty + 8 * ri;
        int n = tile * 64 + r;
        float y[4];
        float s = 0.f, ssq = 0.f;
#pragma unroll
        for (int ci = 0; ci < 4; ++ci) {
            y[ci] = acc[ri][ci] + pb[tx + 32 * ci];
            s += y[ci];
            ssq += y[ci] * y[ci];
        }
#pragma unroll
        for (int m = 1; m < 32; m <<= 1) {
            s += __shfl_xor(s, m);
            ssq += __shfl_xor(ssq, m);
        }
        float mean = s * (1.0f / 128.0f);
        float var = ssq * (1.0f / 128.0f) - mean * mean;
        float rstd = rsqrtf(var + 1e-5f);
        int a = n >> 6, b = (n >> 3) & 7, c = n & 7;
        int od = (wd * 8 + a + 4) & 31, oh = (wh * 8 + b + 4) & 31, ow = (ww * 8 + c + 4) & 31;
        int off = ((od * 32 + oh) * 32 + ow) * 128;
#pragma unroll
        for (int ci = 0; ci < 4; ++ci) {
            int col = tx + 32 * ci;
            float ln = (y[ci] - mean) * rstd * n1w[col] + n1b[col];
            float o = x[off + col] + ln;
            out[off + col] = o;
            Xb[off + col] = f2bf(o);
        }
    }
}

// ---------------- K4: bf16-MFMA MLP (fc1+gelu+fc2) + LN(norm2) + residual ----------------
// grid 256 blocks x 256 threads; wave = 32 tokens (2 groups of 16); no __syncthreads.
// Swapped operands: C col = token, row = out-channel; H round-trips via wave-private LDS.
__global__ void __launch_bounds__(256) k_mlp(
    const unsigned short* __restrict__ Xb, const unsigned short* __restrict__ W1b,
    const unsigned short* __restrict__ W2b, const float* __restrict__ b1f,
    const float* __restrict__ b2f, const float* __restrict__ n2w,
    const float* __restrict__ n2b, float* __restrict__ out) {
    const int tid = threadIdx.x;
    const int wv = tid >> 6;
    const int lane = tid & 63;
    const int qL = lane & 15;   // token-in-group (B col) / oc row for A-fragments
    const int g = lane >> 4;

    __shared__ __align__(16) unsigned short Hl[4][2][16][136];  // wave-private H chunk

    const int tok0 = blockIdx.x * 128 + wv * 32;

    // X B-fragments: lane holds token col = tok0+tg*16+qL, k contiguous
    bf16x8 bX[2][4];
#pragma unroll
    for (int tg = 0; tg < 2; ++tg)
#pragma unroll
        for (int kk = 0; kk < 4; ++kk)
            bX[tg][kk] = *(const bf16x8*)(Xb + (size_t)(tok0 + tg * 16 + qL) * 128 + kk * 32 + 8 * g);

    f32x4 accM[2][8];
#pragma unroll
    for (int tg = 0; tg < 2; ++tg)
#pragma unroll
        for (int t = 0; t < 8; ++t) accM[tg][t] = (f32x4){0.f, 0.f, 0.f, 0.f};

    for (int c4 = 0; c4 < 4; ++c4) {   // 128-oc chunk of fc1 / 128-k chunk of fc2
        // ---- fc1 chunk: H^T tiles = mfma(W1 rows, X cols) ----
#pragma unroll
        for (int t = 0; t < 8; ++t) {
            const int oc0 = c4 * 128 + t * 16;
            f32x4 a1[2] = {(f32x4){0.f, 0.f, 0.f, 0.f}, (f32x4){0.f, 0.f, 0.f, 0.f}};
#pragma unroll
            for (int kk = 0; kk < 4; ++kk) {
                bf16x8 w1f = *(const bf16x8*)(W1b + (size_t)(oc0 + qL) * 128 + kk * 32 + 8 * g);
                a1[0] = __builtin_amdgcn_mfma_f32_16x16x32_bf16(w1f, bX[0][kk], a1[0], 0, 0, 0);
                a1[1] = __builtin_amdgcn_mfma_f32_16x16x32_bf16(w1f, bX[1][kk], a1[1], 0, 0, 0);
            }
            float4 b1v = *(const float4*)(b1f + oc0 + 4 * g);
#pragma unroll
            for (int tg = 0; tg < 2; ++tg) {
                unsigned short hb[4];
#pragma unroll
                for (int r = 0; r < 4; ++r) {
                    float v = a1[tg][r] + ((const float*)&b1v)[r];
                    float u = 0.7978845608028654f * (v + 0.044715f * v * v * v);
                    u = fminf(u, 15.0f);                     // overflow guard
                    float e = __expf(2.0f * u);
                    hb[r] = f2bf(v * e / (e + 1.0f));        // v * (1+tanh(u))/2
                }
                unsigned int lo = (unsigned int)hb[0] | ((unsigned int)hb[1] << 16);
                unsigned int hi = (unsigned int)hb[2] | ((unsigned int)hb[3] << 16);
                *(uint2*)&Hl[wv][tg][qL][t * 16 + 4 * g] = make_uint2(lo, hi);
            }
        }
        // ---- fc2 partial: M += mfma(W2 rows, H cols) over this 128-k chunk ----
        bf16x8 bH[2][4];
#pragma unroll
        for (int tg = 0; tg < 2; ++tg)
#pragma unroll
            for (int kk = 0; kk < 4; ++kk)
                bH[tg][kk] = *(const bf16x8*)&Hl[wv][tg][qL][kk * 32 + 8 * g];
#pragma unroll
        for (int t2 = 0; t2 < 8; ++t2) {
#pragma unroll
            for (int kk = 0; kk < 4; ++kk) {
                bf16x8 w2f = *(const bf16x8*)(W2b + (size_t)(t2 * 16 + qL) * 512 + c4 * 128 + kk * 32 + 8 * g);
                accM[0][t2] = __builtin_amdgcn_mfma_f32_16x16x32_bf16(w2f, bH[0][kk], accM[0][t2], 0, 0, 0);
                accM[1][t2] = __builtin_amdgcn_mfma_f32_16x16x32_bf16(w2f, bH[1][kk], accM[1][t2], 0, 0, 0);
            }
        }
    }

    // ---- epilogue: +b2, LN(norm2), + residual(out), write out ----
#pragma unroll
    for (int tg = 0; tg < 2; ++tg) {
        const int tok = tok0 + tg * 16 + qL;
        float y[8][4];
        float s = 0.f, ssq = 0.f;
#pragma unroll
        for (int t2 = 0; t2 < 8; ++t2) {
            float4 b2v = *(const float4*)(b2f + t2 * 16 + 4 * g);
#pragma unroll
            for (int r = 0; r < 4; ++r) {
                float v = accM[tg][t2][r] + ((const float*)&b2v)[r];
                y[t2][r] = v;
                s += v;
                ssq += v * v;
            }
        }
        s += __shfl_xor(s, 16);
        s += __shfl_xor(s, 32);
        ssq += __shfl_xor(ssq, 16);
        ssq += __shfl_xor(ssq, 32);
        float mean = s * (1.0f / 128.0f);
        float var = ssq * (1.0f / 128.0f) - mean * mean;
        float rstd = rsqrtf(var + 1e-5f);
#pragma unroll
        for (int t2 = 0; t2 < 8; ++t2) {
            const int oc = t2 * 16 + 4 * g;
            float4 wn = *(const float4*)(n2w + oc);
            float4 bn = *(const float4*)(n2b + oc);
            float4 xr = *(const float4*)(out + (size_t)tok * 128 + oc);
            float4 o;
            o.x = xr.x + (y[t2][0] - mean) * rstd * wn.x + bn.x;
            o.y = xr.y + (y[t2][1] - mean) * rstd * wn.y + bn.y;
            o.z = xr.z + (y[t2][2] - mean) * rstd * wn.z + bn.z;
            o.w = xr.w + (y[t2][3] - mean) * rstd * wn.w + bn.w;
            *(float4*)(out + (size_t)tok * 128 + oc) = o;
        }
    }
}

extern "C" void kernel_launch(void* const* d_in, const int* in_sizes, int n_in, void* d_out,
                              int out_size, void* d_ws, size_t ws_size, hipStream_t stream) {
    const float* x   = (const float*)d_in[0];
    const float* n1w = (const float*)d_in[1];
    const float* n1b = (const float*)d_in[2];
    const float* qw  = (const float*)d_in[3];
    const float* qb  = (const float*)d_in[4];
    const float* ls  = (const float*)d_in[5];
    const float* cw1 = (const float*)d_in[6];
    const float* cb1 = (const float*)d_in[7];
    const float* cw2 = (const float*)d_in[8];
    const float* pw  = (const float*)d_in[9];
    const float* pb  = (const float*)d_in[10];
    const float* n2w = (const float*)d_in[11];
    const float* n2b = (const float*)d_in[12];
    const float* w1  = (const float*)d_in[13];
    const float* b1f = (const float*)d_in[14];
    const float* w2  = (const float*)d_in[15];
    const float* b2f = (const float*)d_in[16];
    float* out = (float*)d_out;

    float* ws = (float*)d_ws;
    float* BT = ws;                                        // 13504 floats
    float* B4 = ws + 13504;                                // 1048576 floats (4x512x512)
    unsigned char* CNT8 = (unsigned char*)(ws + 1062080);  // 32768 bytes (8192 floats)
    unsigned short* Qb = (unsigned short*)(ws + 1070272);  // 4194304 ushort (2097152 floats)
    unsigned short* Kb = (unsigned short*)(ws + 3167424);
    unsigned short* Vt = (unsigned short*)(ws + 5264576);
    float* AO = ws + 7361728;                              // 4194304 floats
    unsigned short* W1b = (unsigned short*)(ws + 11556032);  // 65536 ushort (32768 floats)
    unsigned short* W2b = (unsigned short*)(ws + 11588800);
    unsigned short* Xb  = (unsigned short*)(ws + 11621568); // 4194304 ushort

    k_bias_table<<<3375, 128, 0, stream>>>(cw1, cb1, cw2, BT);
    k_bias_expand<<<1024, 256, 0, stream>>>(BT, B4);
    k_cnt<<<128, 256, 0, stream>>>(CNT8);
    k_wcvt<<<256, 256, 0, stream>>>(w1, w2, W1b, W2b);
    k_qkv<<<dim3(8, 64, 3), 256, 0, stream>>>(x, qw, qb, ls, Qb, Kb, Vt);
    k_attn<<<dim3(8, 4, 64), 256, 0, stream>>>(Qb, Kb, Vt, B4, CNT8, AO);
    k_proj_ln<<<dim3(8, 64), 256, 0, stream>>>(AO, pw, pb, n1w, n1b, x, out, Xb);
    k_mlp<<<256, 256, 0, stream>>>(Xb, W1b, W2b, b1f, b2f, n2w, n2b, out);
}

// Round 4
// 203.731 us; speedup vs baseline: 4.6448x; 1.3014x over previous
//
#include <hip/hip_runtime.h>
#include <math.h>

// SwinV2-3D block: RES=32, WS=8, SHIFT=4, NH=4, DIM=128, windows=64, N=512/window.
// Round 4: bf16-MFMA k_qkv (gather fused, LDS-free) + bf16-MFMA k_proj_ln; attn emits bf16 AOb.

typedef short bf16x8 __attribute__((ext_vector_type(8)));
typedef float f32x4 __attribute__((ext_vector_type(4)));

__device__ __forceinline__ int regionOf(int wb, int a) {
    // shifted-coord region along one axis: 0 if coord<24, 1 if 24<=coord<28, 2 if >=28
    return (wb < 3) ? 0 : ((a < 4) ? 1 : 2);
}

__device__ __forceinline__ unsigned short f2bf(float f) {
    unsigned int u = __float_as_uint(f);
    u += 0x7fffu + ((u >> 16) & 1u);   // RNE (inputs are finite, no NaN handling needed)
    return (unsigned short)(u >> 16);
}

// ---------------- K0: CPB bias table: BT[3375][4] = 16*sigmoid(MLP(ctab)) ----------------
__global__ void k_bias_table(const float* __restrict__ w1, const float* __restrict__ b1,
                             const float* __restrict__ w2, float* __restrict__ BT) {
    int e = blockIdx.x;                       // 0..3374
    int id = e / 225, rem = e % 225, ih = rem / 15, iw = rem % 15;
    float ct[3];
    int ids[3] = {id, ih, iw};
#pragma unroll
    for (int a = 0; a < 3; ++a) {
        float r = (float)(ids[a] - 7) * (8.0f / 7.0f);
        float s = (r > 0.f) ? 1.f : ((r < 0.f) ? -1.f : 0.f);
        ct[a] = s * log2f(fabsf(r) + 1.0f) * (1.0f / 3.0f);   // /log2(8)
    }
    int t = threadIdx.x;                      // 128 threads
    float acc[4] = {0.f, 0.f, 0.f, 0.f};
    for (int j = t; j < 512; j += 128) {
        float hv = ct[0] * w1[j * 3 + 0] + ct[1] * w1[j * 3 + 1] + ct[2] * w1[j * 3 + 2] + b1[j];
        hv = fmaxf(hv, 0.f);
#pragma unroll
        for (int h = 0; h < 4; ++h) acc[h] += hv * w2[h * 512 + j];
    }
    __shared__ float red[4][128];
#pragma unroll
    for (int h = 0; h < 4; ++h) red[h][t] = acc[h];
    __syncthreads();
    if (t < 4) {
        float s = 0.f;
        for (int i = 0; i < 128; ++i) s += red[t][i];
        BT[e * 4 + t] = 16.0f / (1.0f + expf(-s));
    }
}

// ---------------- K0b: expand bias to BIAS4[h][m][n] (4 x 512 x 512 fp32) ----------------
__global__ void k_bias_expand(const float* __restrict__ BT, float* __restrict__ B4) {
    int idx = blockIdx.x * 256 + threadIdx.x;   // 262144
    int m = idx >> 9, n = idx & 511;
    int an = n >> 6, bn = (n >> 3) & 7, cn = n & 7;
    int am = m >> 6, bm = (m >> 3) & 7, cm = m & 7;
    int ridx = ((an - am + 7) * 15 + (bn - bm + 7)) * 15 + (cn - cm + 7);
    float4 bv = *(const float4*)(BT + ridx * 4);
    B4[(size_t)(0 * 512 + m) * 512 + n] = bv.x;
    B4[(size_t)(1 * 512 + m) * 512 + n] = bv.y;
    B4[(size_t)(2 * 512 + m) * 512 + n] = bv.z;
    B4[(size_t)(3 * 512 + m) * 512 + n] = bv.w;
}

// ---------------- K0c: per-(window,token) mask region class, CNT[w][n] uint8 -------------
__global__ void k_cnt(unsigned char* __restrict__ CNT) {
    int idx = blockIdx.x * 256 + threadIdx.x;   // 32768
    int w = idx >> 9, n = idx & 511;
    int wd = w >> 4, wh = (w >> 2) & 3, ww = w & 3;
    int a = n >> 6, b = (n >> 3) & 7, c = n & 7;
    CNT[idx] = (unsigned char)(regionOf(wd, a) * 9 + regionOf(wh, b) * 3 + regionOf(ww, c));
}

// ---------------- K0d: cast weights to bf16 ----------------
__global__ void k_wcvt(const float* __restrict__ w1, const float* __restrict__ w2,
                       const float* __restrict__ qw, const float* __restrict__ pw,
                       unsigned short* __restrict__ W1b, unsigned short* __restrict__ W2b,
                       unsigned short* __restrict__ Wqb, unsigned short* __restrict__ Pwb) {
    int idx = blockIdx.x * 256 + threadIdx.x;   // 65536
    W1b[idx] = f2bf(w1[idx]);
    W2b[idx] = f2bf(w2[idx]);
    if (idx < 49152) Wqb[idx] = f2bf(qw[idx]);
    if (idx < 16384) Pwb[idx] = f2bf(pw[idx]);
}

// ---------------- K1: bf16-MFMA QKV with fused roll+window gather (LDS-free) -------------
// grid 512 blocks x 256; wave = 16 tokens of one window. 96 MFMA/wave.
__global__ void __launch_bounds__(256) k_qkv(
    const float* __restrict__ x, const unsigned short* __restrict__ Wqb,
    const float* __restrict__ qb, const float* __restrict__ ls,
    unsigned short* __restrict__ Qb, unsigned short* __restrict__ Kb,
    unsigned short* __restrict__ Vt) {
    const int tid = threadIdx.x;
    const int wv = tid >> 6, lane = tid & 63;
    const int qL = lane & 15, g = lane >> 4;
    const int tokG = blockIdx.x * 64 + wv * 16;
    const int w = tokG >> 9, n0 = tokG & 511;
    const int wd = w >> 4, wh = (w >> 2) & 3, ww = w & 3;
    const int n = n0 + qL;
    const int a = n >> 6, b = (n >> 3) & 7, c = n & 7;
    const int od = (wd * 8 + a + 4) & 31, oh = (wh * 8 + b + 4) & 31, ow = (ww * 8 + c + 4) & 31;
    const float* xrow = x + ((od * 32 + oh) * 32 + ow) * 128;

    // X B-fragments: lane holds token col qL, k = ch contiguous (fp32 -> bf16 in-register)
    bf16x8 bX[4];
#pragma unroll
    for (int kk = 0; kk < 4; ++kk) {
        float4 f0 = *(const float4*)(xrow + kk * 32 + 8 * g);
        float4 f1 = *(const float4*)(xrow + kk * 32 + 8 * g + 4);
        bf16x8 v;
        v[0] = (short)f2bf(f0.x); v[1] = (short)f2bf(f0.y);
        v[2] = (short)f2bf(f0.z); v[3] = (short)f2bf(f0.w);
        v[4] = (short)f2bf(f1.x); v[5] = (short)f2bf(f1.y);
        v[6] = (short)f2bf(f1.z); v[7] = (short)f2bf(f1.w);
        bX[kk] = v;
    }

    // ---- q,k slabs: per head, 2 tiles (d 0..15, 16..31), cosine norm in-register ----
#pragma unroll
    for (int s = 0; s < 2; ++s) {
        unsigned short* dst = s ? Kb : Qb;
#pragma unroll
        for (int ci = 0; ci < 4; ++ci) {
            const int ch0 = s * 128 + ci * 32;
            f32x4 aL = {0.f, 0.f, 0.f, 0.f}, aH = {0.f, 0.f, 0.f, 0.f};
#pragma unroll
            for (int kk = 0; kk < 4; ++kk) {
                bf16x8 wL = *(const bf16x8*)(Wqb + (size_t)(ch0 + qL) * 128 + kk * 32 + 8 * g);
                bf16x8 wH = *(const bf16x8*)(Wqb + (size_t)(ch0 + 16 + qL) * 128 + kk * 32 + 8 * g);
                aL = __builtin_amdgcn_mfma_f32_16x16x32_bf16(wL, bX[kk], aL, 0, 0, 0);
                aH = __builtin_amdgcn_mfma_f32_16x16x32_bf16(wH, bX[kk], aH, 0, 0, 0);
            }
            float4 bL = *(const float4*)(qb + ch0 + 4 * g);
            float4 bH = *(const float4*)(qb + ch0 + 16 + 4 * g);
            float vL[4], vH[4], ss = 0.f;
#pragma unroll
            for (int r = 0; r < 4; ++r) {
                vL[r] = aL[r] + ((const float*)&bL)[r];
                vH[r] = aH[r] + ((const float*)&bH)[r];
                ss += vL[r] * vL[r] + vH[r] * vH[r];
            }
            ss += __shfl_xor(ss, 16);
            ss += __shfl_xor(ss, 32);
            float rn = 1.0f / (sqrtf(ss) + 1e-12f);
            if (s == 0) rn *= expf(fminf(ls[ci], 4.6051701859880914f));
            unsigned int l0 = (unsigned int)f2bf(vL[0] * rn) | ((unsigned int)f2bf(vL[1] * rn) << 16);
            unsigned int l1 = (unsigned int)f2bf(vL[2] * rn) | ((unsigned int)f2bf(vL[3] * rn) << 16);
            unsigned int h0 = (unsigned int)f2bf(vH[0] * rn) | ((unsigned int)f2bf(vH[1] * rn) << 16);
            unsigned int h1 = (unsigned int)f2bf(vH[2] * rn) | ((unsigned int)f2bf(vH[3] * rn) << 16);
            size_t base = ((size_t)(w * 4 + ci) * 512 + n) * 32;
            *(uint2*)(dst + base + 4 * g) = make_uint2(l0, l1);
            *(uint2*)(dst + base + 16 + 4 * g) = make_uint2(h0, h1);
        }
    }
    // ---- v slab: transpose-scatter to Vt[wh][d][n] ----
#pragma unroll
    for (int ci = 0; ci < 4; ++ci) {
        const int ch0 = 256 + ci * 32;
        f32x4 aL = {0.f, 0.f, 0.f, 0.f}, aH = {0.f, 0.f, 0.f, 0.f};
#pragma unroll
        for (int kk = 0; kk < 4; ++kk) {
            bf16x8 wL = *(const bf16x8*)(Wqb + (size_t)(ch0 + qL) * 128 + kk * 32 + 8 * g);
            bf16x8 wH = *(const bf16x8*)(Wqb + (size_t)(ch0 + 16 + qL) * 128 + kk * 32 + 8 * g);
            aL = __builtin_amdgcn_mfma_f32_16x16x32_bf16(wL, bX[kk], aL, 0, 0, 0);
            aH = __builtin_amdgcn_mfma_f32_16x16x32_bf16(wH, bX[kk], aH, 0, 0, 0);
        }
        float4 bL = *(const float4*)(qb + ch0 + 4 * g);
        float4 bH = *(const float4*)(qb + ch0 + 16 + 4 * g);
        const size_t vtb = (size_t)(w * 4 + ci) * 32 * 512;
#pragma unroll
        for (int r = 0; r < 4; ++r) {
            Vt[vtb + (size_t)(4 * g + r) * 512 + n] = f2bf(aL[r] + ((const float*)&bL)[r]);
            Vt[vtb + (size_t)(16 + 4 * g + r) * 512 + n] = f2bf(aH[r] + ((const float*)&bH)[r]);
        }
    }
}

// ---------------- K2: bf16-MFMA flash attention (emits bf16 AOb) ----------------
// grid (8 q-octs of 64 rows, 4 heads, 64 windows), block 256 = 4 waves, wave = 16 q-rows.
__global__ void __launch_bounds__(256) k_attn(
    const unsigned short* __restrict__ Qb, const unsigned short* __restrict__ Kb,
    const unsigned short* __restrict__ Vt, const float* __restrict__ B4,
    const unsigned char* __restrict__ CNT, unsigned short* __restrict__ AOb) {
    const int qoct = blockIdx.x;  // 0..7
    const int h = blockIdx.y;     // 0..3
    const int w = blockIdx.z;     // 0..63
    const int tid = threadIdx.x;
    const int wv = tid >> 6;
    const int lane = tid & 63;
    const int qL = lane & 15;     // q (QK-C col / PV-A row / V-B col d)
    const int g = lane >> 4;      // k-group

    __shared__ __align__(16) unsigned short Pbuf[4][16][72];  // per-wave P tile, pitch-padded

    const int q0 = qoct * 64 + wv * 16;
    const int wh4 = w * 4 + h;
    const size_t qk_base = (size_t)wh4 * 512 * 32;
    const size_t vt_base = (size_t)wh4 * 32 * 512;

    // Q B-fragment: lane holds col q=lane&15, k = d = 8g..8g+7 -> Q[q][8g..] contiguous
    bf16x8 bQ = *(const bf16x8*)(Qb + qk_base + (size_t)(q0 + qL) * 32 + 8 * g);

    const int cq = CNT[w * 512 + q0 + qL];
    const float* Bh = B4 + (size_t)h * 512 * 512;
    const unsigned char* Cw = CNT + w * 512;
    unsigned short* prow = &Pbuf[wv][qL][0];

    float m_run = -1e30f, l_run = 0.f;
    f32x4 o0 = {0.f, 0.f, 0.f, 0.f}, o1 = {0.f, 0.f, 0.f, 0.f};

    for (int c = 0; c < 8; ++c) {
        const int m0 = c * 64;
        f32x4 st[4];
        // S^T tiles: A = K[16m x 32d] (lane row m=lane&15, k=d=8g+e), B = bQ
#pragma unroll
        for (int t = 0; t < 4; ++t) {
            bf16x8 aK = *(const bf16x8*)(Kb + qk_base + (size_t)(m0 + t * 16 + qL) * 32 + 8 * g);
            st[t] = __builtin_amdgcn_mfma_f32_16x16x32_bf16(
                aK, bQ, (f32x4){0.f, 0.f, 0.f, 0.f}, 0, 0, 0);
        }
        // + bias + mask; chunk max (lane holds m = m0 + t*16 + 4g + r for its q)
        float cmax = -1e30f;
#pragma unroll
        for (int t = 0; t < 4; ++t) {
            int mb = m0 + t * 16 + 4 * g;
#pragma unroll
            for (int r = 0; r < 4; ++r) {
                float sv = st[t][r] + Bh[(size_t)(mb + r) * 512 + q0 + qL];
                sv += (Cw[mb + r] == cq) ? 0.f : -100.f;
                st[t][r] = sv;
                cmax = fmaxf(cmax, sv);
            }
        }
        cmax = fmaxf(cmax, __shfl_xor(cmax, 16));
        cmax = fmaxf(cmax, __shfl_xor(cmax, 32));
        float mnew = fmaxf(m_run, cmax);
        float corr = __expf(m_run - mnew);
        float csum = 0.f;
#pragma unroll
        for (int t = 0; t < 4; ++t) {
#pragma unroll
            for (int r = 0; r < 4; ++r) {
                float p = __expf(st[t][r] - mnew);
                st[t][r] = p;
                csum += p;
            }
        }
        csum += __shfl_xor(csum, 16);
        csum += __shfl_xor(csum, 32);
        l_run = l_run * corr + csum;
        m_run = mnew;
        // rescale O: row q' = 4g+r needs corr owned by lanes with lane&15 == q'
#pragma unroll
        for (int r = 0; r < 4; ++r) {
            float cr = __shfl(corr, 4 * g + r, 64);
            o0[r] *= cr;
            o1[r] *= cr;
        }
        // P -> bf16 -> wave-private LDS (elem index == m - m0)
#pragma unroll
        for (int t = 0; t < 4; ++t) {
            unsigned int lo = (unsigned int)f2bf(st[t][0]) | ((unsigned int)f2bf(st[t][1]) << 16);
            unsigned int hi = (unsigned int)f2bf(st[t][2]) | ((unsigned int)f2bf(st[t][3]) << 16);
            *(uint2*)(prow + t * 16 + 4 * g) = make_uint2(lo, hi);
        }
        // PV: A = P[16q x 32m] from Pbuf, B = V[32m x 16d] from Vt (both 16B reads)
#pragma unroll
        for (int s = 0; s < 2; ++s) {
            bf16x8 pa = *(const bf16x8*)(prow + s * 32 + 8 * g);
            bf16x8 bv0 = *(const bf16x8*)(Vt + vt_base + (size_t)qL * 512 + m0 + s * 32 + 8 * g);
            bf16x8 bv1 = *(const bf16x8*)(Vt + vt_base + (size_t)(16 + qL) * 512 + m0 + s * 32 + 8 * g);
            o0 = __builtin_amdgcn_mfma_f32_16x16x32_bf16(pa, bv0, o0, 0, 0, 0);
            o1 = __builtin_amdgcn_mfma_f32_16x16x32_bf16(pa, bv1, o1, 0, 0, 0);
        }
    }
    // epilogue: divide by row-sum; lane holds (d = qL [+16], q = 4g+r); bf16 out
    float linv = 1.0f / l_run;
#pragma unroll
    for (int r = 0; r < 4; ++r) {
        float lr = __shfl(linv, 4 * g + r, 64);
        int q = q0 + 4 * g + r;
        AOb[(size_t)(w * 512 + q) * 128 + h * 32 + qL] = f2bf(o0[r] * lr);
        AOb[(size_t)(w * 512 + q) * 128 + h * 32 + 16 + qL] = f2bf(o1[r] * lr);
    }
}

// ---------------- K3: bf16-MFMA proj + LN(norm1) + residual, scatter (+bf16 Xb) ---------
// grid 512 blocks x 256; wave = 16 tokens. 32 MFMA/wave. LDS-free.
__global__ void __launch_bounds__(256) k_proj_ln(
    const unsigned short* __restrict__ AOb, const unsigned short* __restrict__ Pwb,
    const float* __restrict__ pb, const float* __restrict__ n1w, const float* __restrict__ n1b,
    const float* __restrict__ x, float* __restrict__ out, unsigned short* __restrict__ Xb) {
    const int tid = threadIdx.x;
    const int wv = tid >> 6, lane = tid & 63;
    const int qL = lane & 15, g = lane >> 4;
    const int tokG = blockIdx.x * 64 + wv * 16;
    const int tok = tokG + qL;
    const int w = tokG >> 9;
    const int n = (tokG & 511) + qL;
    const int wd = w >> 4, wh = (w >> 2) & 3, ww = w & 3;

    bf16x8 bA[4];
#pragma unroll
    for (int kk = 0; kk < 4; ++kk)
        bA[kk] = *(const bf16x8*)(AOb + (size_t)tok * 128 + kk * 32 + 8 * g);

    f32x4 acc[8];
#pragma unroll
    for (int t = 0; t < 8; ++t) acc[t] = (f32x4){0.f, 0.f, 0.f, 0.f};
#pragma unroll
    for (int t = 0; t < 8; ++t) {
#pragma unroll
        for (int kk = 0; kk < 4; ++kk) {
            bf16x8 wf = *(const bf16x8*)(Pwb + (size_t)(t * 16 + qL) * 128 + kk * 32 + 8 * g);
            acc[t] = __builtin_amdgcn_mfma_f32_16x16x32_bf16(wf, bA[kk], acc[t], 0, 0, 0);
        }
    }

    float y[8][4];
    float s = 0.f, ssq = 0.f;
#pragma unroll
    for (int t = 0; t < 8; ++t) {
        float4 pbv = *(const float4*)(pb + t * 16 + 4 * g);
#pragma unroll
        for (int r = 0; r < 4; ++r) {
            float v = acc[t][r] + ((const float*)&pbv)[r];
            y[t][r] = v;
            s += v;
            ssq += v * v;
        }
    }
    s += __shfl_xor(s, 16);
    s += __shfl_xor(s, 32);
    ssq += __shfl_xor(ssq, 16);
    ssq += __shfl_xor(ssq, 32);
    float mean = s * (1.0f / 128.0f);
    float var = ssq * (1.0f / 128.0f) - mean * mean;
    float rstd = rsqrtf(var + 1e-5f);

    int a = n >> 6, b = (n >> 3) & 7, c = n & 7;
    int od = (wd * 8 + a + 4) & 31, oh = (wh * 8 + b + 4) & 31, ow = (ww * 8 + c + 4) & 31;
    int off = ((od * 32 + oh) * 32 + ow) * 128;
#pragma unroll
    for (int t = 0; t < 8; ++t) {
        int col = t * 16 + 4 * g;
        float4 wn = *(const float4*)(n1w + col);
        float4 bn = *(const float4*)(n1b + col);
        float4 xr = *(const float4*)(x + off + col);
        float4 o;
        o.x = xr.x + (y[t][0] - mean) * rstd * wn.x + bn.x;
        o.y = xr.y + (y[t][1] - mean) * rstd * wn.y + bn.y;
        o.z = xr.z + (y[t][2] - mean) * rstd * wn.z + bn.z;
        o.w = xr.w + (y[t][3] - mean) * rstd * wn.w + bn.w;
        *(float4*)(out + off + col) = o;
        unsigned int p0 = (unsigned int)f2bf(o.x) | ((unsigned int)f2bf(o.y) << 16);
        unsigned int p1 = (unsigned int)f2bf(o.z) | ((unsigned int)f2bf(o.w) << 16);
        *(uint2*)(Xb + off + col) = make_uint2(p0, p1);
    }
}

// ---------------- K4: bf16-MFMA MLP (fc1+gelu+fc2) + LN(norm2) + residual ----------------
// grid 256 blocks x 256 threads; wave = 32 tokens (2 groups of 16); no __syncthreads.
__global__ void __launch_bounds__(256) k_mlp(
    const unsigned short* __restrict__ Xb, const unsigned short* __restrict__ W1b,
    const unsigned short* __restrict__ W2b, const float* __restrict__ b1f,
    const float* __restrict__ b2f, const float* __restrict__ n2w,
    const float* __restrict__ n2b, float* __restrict__ out) {
    const int tid = threadIdx.x;
    const int wv = tid >> 6;
    const int lane = tid & 63;
    const int qL = lane & 15;   // token-in-group (B col) / oc row for A-fragments
    const int g = lane >> 4;

    __shared__ __align__(16) unsigned short Hl[4][2][16][136];  // wave-private H chunk

    const int tok0 = blockIdx.x * 128 + wv * 32;

    // X B-fragments: lane holds token col = tok0+tg*16+qL, k contiguous
    bf16x8 bX[2][4];
#pragma unroll
    for (int tg = 0; tg < 2; ++tg)
#pragma unroll
        for (int kk = 0; kk < 4; ++kk)
            bX[tg][kk] = *(const bf16x8*)(Xb + (size_t)(tok0 + tg * 16 + qL) * 128 + kk * 32 + 8 * g);

    f32x4 accM[2][8];
#pragma unroll
    for (int tg = 0; tg < 2; ++tg)
#pragma unroll
        for (int t = 0; t < 8; ++t) accM[tg][t] = (f32x4){0.f, 0.f, 0.f, 0.f};

    for (int c4 = 0; c4 < 4; ++c4) {   // 128-oc chunk of fc1 / 128-k chunk of fc2
        // ---- fc1 chunk: H^T tiles = mfma(W1 rows, X cols) ----
#pragma unroll
        for (int t = 0; t < 8; ++t) {
            const int oc0 = c4 * 128 + t * 16;
            f32x4 a1[2] = {(f32x4){0.f, 0.f, 0.f, 0.f}, (f32x4){0.f, 0.f, 0.f, 0.f}};
#pragma unroll
            for (int kk = 0; kk < 4; ++kk) {
                bf16x8 w1f = *(const bf16x8*)(W1b + (size_t)(oc0 + qL) * 128 + kk * 32 + 8 * g);
                a1[0] = __builtin_amdgcn_mfma_f32_16x16x32_bf16(w1f, bX[0][kk], a1[0], 0, 0, 0);
                a1[1] = __builtin_amdgcn_mfma_f32_16x16x32_bf16(w1f, bX[1][kk], a1[1], 0, 0, 0);
            }
            float4 b1v = *(const float4*)(b1f + oc0 + 4 * g);
#pragma unroll
            for (int tg = 0; tg < 2; ++tg) {
                unsigned short hb[4];
#pragma unroll
                for (int r = 0; r < 4; ++r) {
                    float v = a1[tg][r] + ((const float*)&b1v)[r];
                    float u = 0.7978845608028654f * (v + 0.044715f * v * v * v);
                    u = fminf(u, 15.0f);                     // overflow guard
                    float e = __expf(2.0f * u);
                    hb[r] = f2bf(v * e / (e + 1.0f));        // v * (1+tanh(u))/2
                }
                unsigned int lo = (unsigned int)hb[0] | ((unsigned int)hb[1] << 16);
                unsigned int hi = (unsigned int)hb[2] | ((unsigned int)hb[3] << 16);
                *(uint2*)&Hl[wv][tg][qL][t * 16 + 4 * g] = make_uint2(lo, hi);
            }
        }
        // ---- fc2 partial: M += mfma(W2 rows, H cols) over this 128-k chunk ----
        bf16x8 bH[2][4];
#pragma unroll
        for (int tg = 0; tg < 2; ++tg)
#pragma unroll
            for (int kk = 0; kk < 4; ++kk)
                bH[tg][kk] = *(const bf16x8*)&Hl[wv][tg][qL][kk * 32 + 8 * g];
#pragma unroll
        for (int t2 = 0; t2 < 8; ++t2) {
#pragma unroll
            for (int kk = 0; kk < 4; ++kk) {
                bf16x8 w2f = *(const bf16x8*)(W2b + (size_t)(t2 * 16 + qL) * 512 + c4 * 128 + kk * 32 + 8 * g);
                accM[0][t2] = __builtin_amdgcn_mfma_f32_16x16x32_bf16(w2f, bH[0][kk], accM[0][t2], 0, 0, 0);
                accM[1][t2] = __builtin_amdgcn_mfma_f32_16x16x32_bf16(w2f, bH[1][kk], accM[1][t2], 0, 0, 0);
            }
        }
    }

    // ---- epilogue: +b2, LN(norm2), + residual(out), write out ----
#pragma unroll
    for (int tg = 0; tg < 2; ++tg) {
        const int tok = tok0 + tg * 16 + qL;
        float y[8][4];
        float s = 0.f, ssq = 0.f;
#pragma unroll
        for (int t2 = 0; t2 < 8; ++t2) {
            float4 b2v = *(const float4*)(b2f + t2 * 16 + 4 * g);
#pragma unroll
            for (int r = 0; r < 4; ++r) {
                float v = accM[tg][t2][r] + ((const float*)&b2v)[r];
                y[t2][r] = v;
                s += v;
                ssq += v * v;
            }
        }
        s += __shfl_xor(s, 16);
        s += __shfl_xor(s, 32);
        ssq += __shfl_xor(ssq, 16);
        ssq += __shfl_xor(ssq, 32);
        float mean = s * (1.0f / 128.0f);
        float var = ssq * (1.0f / 128.0f) - mean * mean;
        float rstd = rsqrtf(var + 1e-5f);
#pragma unroll
        for (int t2 = 0; t2 < 8; ++t2) {
            const int oc = t2 * 16 + 4 * g;
            float4 wn = *(const float4*)(n2w + oc);
            float4 bn = *(const float4*)(n2b + oc);
            float4 xr = *(const float4*)(out + (size_t)tok * 128 + oc);
            float4 o;
            o.x = xr.x + (y[t2][0] - mean) * rstd * wn.x + bn.x;
            o.y = xr.y + (y[t2][1] - mean) * rstd * wn.y + bn.y;
            o.z = xr.z + (y[t2][2] - mean) * rstd * wn.z + bn.z;
            o.w = xr.w + (y[t2][3] - mean) * rstd * wn.w + bn.w;
            *(float4*)(out + (size_t)tok * 128 + oc) = o;
        }
    }
}

extern "C" void kernel_launch(void* const* d_in, const int* in_sizes, int n_in, void* d_out,
                              int out_size, void* d_ws, size_t ws_size, hipStream_t stream) {
    const float* x   = (const float*)d_in[0];
    const float* n1w = (const float*)d_in[1];
    const float* n1b = (const float*)d_in[2];
    const float* qw  = (const float*)d_in[3];
    const float* qb  = (const float*)d_in[4];
    const float* ls  = (const float*)d_in[5];
    const float* cw1 = (const float*)d_in[6];
    const float* cb1 = (const float*)d_in[7];
    const float* cw2 = (const float*)d_in[8];
    const float* pw  = (const float*)d_in[9];
    const float* pb  = (const float*)d_in[10];
    const float* n2w = (const float*)d_in[11];
    const float* n2b = (const float*)d_in[12];
    const float* w1  = (const float*)d_in[13];
    const float* b1f = (const float*)d_in[14];
    const float* w2  = (const float*)d_in[15];
    const float* b2f = (const float*)d_in[16];
    float* out = (float*)d_out;

    float* ws = (float*)d_ws;
    float* BT = ws;                                        // 13504 floats
    float* B4 = ws + 13504;                                // 1048576 floats (4x512x512)
    unsigned char* CNT8 = (unsigned char*)(ws + 1062080);  // 32768 bytes (8192 floats)
    unsigned short* Qb  = (unsigned short*)(ws + 1070272); // 4194304 ushort (2097152 floats)
    unsigned short* Kb  = (unsigned short*)(ws + 3167424);
    unsigned short* Vt  = (unsigned short*)(ws + 5264576);
    unsigned short* AOb = (unsigned short*)(ws + 7361728);
    unsigned short* W1b = (unsigned short*)(ws + 9458880); // 65536 ushort (32768 floats)
    unsigned short* W2b = (unsigned short*)(ws + 9491648);
    unsigned short* Wqb = (unsigned short*)(ws + 9524416); // 49152 ushort (24576 floats)
    unsigned short* Pwb = (unsigned short*)(ws + 9548992); // 16384 ushort (8192 floats)
    unsigned short* Xb  = (unsigned short*)(ws + 9557184); // 4194304 ushort

    k_bias_table<<<3375, 128, 0, stream>>>(cw1, cb1, cw2, BT);
    k_bias_expand<<<1024, 256, 0, stream>>>(BT, B4);
    k_cnt<<<128, 256, 0, stream>>>(CNT8);
    k_wcvt<<<256, 256, 0, stream>>>(w1, w2, qw, pw, W1b, W2b, Wqb, Pwb);
    k_qkv<<<512, 256, 0, stream>>>(x, Wqb, qb, ls, Qb, Kb, Vt);
    k_attn<<<dim3(8, 4, 64), 256, 0, stream>>>(Qb, Kb, Vt, B4, CNT8, AOb);
    k_proj_ln<<<512, 256, 0, stream>>>(AOb, Pwb, pb, n1w, n1b, x, out, Xb);
    k_mlp<<<256, 256, 0, stream>>>(Xb, W1b, W2b, b1f, b2f, n2w, n2b, out);
}